// Round 10
// baseline (1041.307 us; speedup 1.0000x reference)
//
#include <hip/hip_runtime.h>
#include <hip/hip_bf16.h>
#include <math.h>

using bf16 = __hip_bfloat16;

typedef __attribute__((ext_vector_type(8))) short short8;   // 8 bf16 (4 VGPRs)
typedef __attribute__((ext_vector_type(4))) float float4v;  // MFMA acc

static constexpr int kNA  = 20000;
static constexpr int kNP  = 40000;
static constexpr int kEWB = 150000;
static constexpr int kEW  = 150000;
static constexpr int kEC  = 300000;

// ---- canonical bf16 input region ----
static constexpr int kNSeg = 21;
static constexpr int kSegN[kNSeg] = {
  150000, 150000, 300000,           // ew_wb, ew_w, ew_c
  131072, 512,                      // adW, adb
  262144, 1024,                     // kW, kb
  262144, 1024,                     // qW, qb
  262144, 1024,                     // mW, mb
  262144, 1024,                     // aW, ab
  24,                               // wpri
  98304, 98304,                     // watt, wmsg
  6, 1024, 1024,                    // skip, lng, lnb
  16384, 64                         // outW, outb
};
static constexpr size_t kOff(int s) {
  size_t o = 0;
  for (int i = 0; i < s; ++i) o += (size_t)kSegN[i];
  return o;
}
static constexpr size_t kCanonTotal = kOff(kNSeg);

struct CanonArgs {
  const void* src[kNSeg];
  int n[kNSeg];
  unsigned dstOff[kNSeg];
};
struct TransArgs {
  const bf16* src[10];
  bf16* dst[10];
};
// per-slab GEMM output descriptor (slab = 128 output cols)
struct GemmDesc {
  const short* wt;   // [128][256] n-major slab
  const bf16* bias;  // 128 entries (slab-local)
  void* c;           // output base
  int ldc;           // in elements
  int coff;          // global col offset of this slab in C
  int act;           // 1 = gelu
  int otype;         // 0 = bf16, 1 = fp32
  int pad;
};
struct MultiDesc { GemmDesc d[6]; };
// three-relation scan descriptor
struct ScanArgs {
  int* deg[3];   // degree arrays (also cursor output)
  int* offs[3];  // offsets (N+1)
  int* bsums;    // [3][32] block sums
  int N[3];
};

__device__ __forceinline__ float toF(float x) { return x; }
__device__ __forceinline__ float toF(bf16 x)  { return __bfloat162float(x); }
__device__ __forceinline__ float bits2f(unsigned short b) {
  unsigned int u = ((unsigned int)b) << 16;
  return __uint_as_float(u);
}
__device__ __forceinline__ float sigmoidf_(float x) { return 1.0f / (1.0f + expf(-x)); }
__device__ __forceinline__ float gelu_exact(float x) {
  return 0.5f * x * (1.0f + erff(x * 0.70710678118654752f));
}

// -------------------------------------------------------------------------
// Input-dtype sniffer. flags: [0]=isBf16 [1]=1
// -------------------------------------------------------------------------
__global__ __launch_bounds__(256) void detect_dtype(
    const unsigned* __restrict__ x, unsigned* __restrict__ flags)
{
  __shared__ int cnt;
  if (threadIdx.x == 0) cnt = 0;
  __syncthreads();
  unsigned w = x[threadIdx.x];
  unsigned e = (w >> 7) & 0xFFu;
  if (e >= 110u && e <= 140u) atomicAdd(&cnt, 1);
  __syncthreads();
  if (threadIdx.x == 0) {
    flags[0] = (cnt >= 128) ? 1u : 0u;
    flags[1] = 1u;
  }
}

__global__ __launch_bounds__(256) void canon_kernel(
    CanonArgs a, bf16* __restrict__ dst, const unsigned* __restrict__ flags)
{
  const int s = blockIdx.y;
  const int i = blockIdx.x * 256 + threadIdx.x;
  if (i >= a.n[s]) return;
  bf16 v;
  if (flags[0]) v = ((const bf16*)a.src[s])[i];
  else          v = __float2bfloat16(((const float*)a.src[s])[i]);
  dst[a.dstOff[s] + i] = v;
}

// -------------------------------------------------------------------------
// Batched 256x256 weight transpose: dst[n][k] = src[k][n]. grid (4,4,10).
// -------------------------------------------------------------------------
__global__ __launch_bounds__(256) void transpose_w(TransArgs ta)
{
  const int m = blockIdx.z;
  const short* src = (const short*)ta.src[m];
  short* dst = (short*)ta.dst[m];
  const int k0 = blockIdx.x * 64, n0 = blockIdx.y * 64;
  __shared__ short tile[64][65];
  const int tx = threadIdx.x & 63, ty = threadIdx.x >> 6;
  for (int i = ty; i < 64; i += 4)
    tile[i][tx] = src[(size_t)(k0 + i) * 256 + n0 + tx];
  __syncthreads();
  for (int i = ty; i < 64; i += 4)
    dst[(size_t)(n0 + i) * 256 + k0 + tx] = tile[tx][i];
}

// -------------------------------------------------------------------------
// CSR build: histogram -> 3-level parallel scan -> gather-scatter.
// -------------------------------------------------------------------------
__global__ __launch_bounds__(256) void csr_hist(
    const int* __restrict__ dst, int E, int* __restrict__ cnt)
{
  const int i = blockIdx.x * 256 + threadIdx.x;
  if (i < E) atomicAdd(&cnt[dst[i]], 1);
}

__global__ __launch_bounds__(256) void scan_l1(ScanArgs a)
{
  const int rel = blockIdx.y;
  const int N = a.N[rel];
  const int t = threadIdx.x;
  const int lane = t & 63;
  const int wid = t >> 6;
  const int i0 = blockIdx.x * 2048 + t * 8;
  const int* deg = a.deg[rel];
  int v[8];
  int T = 0;
  #pragma unroll
  for (int j = 0; j < 8; ++j) {
    v[j] = (i0 + j < N) ? deg[i0 + j] : 0;
    T += v[j];
  }
  int incl = T;
  #pragma unroll
  for (int off = 1; off < 64; off <<= 1) {
    const int u = __shfl_up(incl, off);
    if (lane >= off) incl += u;
  }
  __shared__ int wsum[4];
  if (lane == 63) wsum[wid] = incl;
  __syncthreads();
  int woff = 0;
  #pragma unroll
  for (int wp = 0; wp < 4; ++wp) if (wp < wid) woff += wsum[wp];
  int run = woff + incl - T;
  int* offs = a.offs[rel];
  #pragma unroll
  for (int j = 0; j < 8; ++j) {
    if (i0 + j < N) offs[i0 + j] = run;
    run += v[j];
  }
  if (t == 0)
    a.bsums[rel * 32 + blockIdx.x] = wsum[0] + wsum[1] + wsum[2] + wsum[3];
}

__global__ __launch_bounds__(64) void scan_l2(int* __restrict__ bsums,
                                              int* __restrict__ totals)
{
  const int rel = blockIdx.x;
  const int lane = threadIdx.x;
  const int v = (lane < 32) ? bsums[rel * 32 + lane] : 0;
  int incl = v;
  #pragma unroll
  for (int off = 1; off < 64; off <<= 1) {
    const int u = __shfl_up(incl, off);
    if (lane >= off) incl += u;
  }
  if (lane < 32) bsums[rel * 32 + lane] = incl - v;
  if (lane == 63) totals[rel] = incl;
}

__global__ __launch_bounds__(256) void scan_l3(ScanArgs a,
                                               const int* __restrict__ totals)
{
  const int rel = blockIdx.y;
  const int N = a.N[rel];
  const int i0 = blockIdx.x * 2048 + threadIdx.x * 8;
  const int boff = a.bsums[rel * 32 + blockIdx.x];
  int* offs = a.offs[rel];
  int* cur = a.deg[rel];
  #pragma unroll
  for (int j = 0; j < 8; ++j) {
    const int idx = i0 + j;
    if (idx < N) {
      const int o = offs[idx] + boff;
      offs[idx] = o;
      cur[idx] = o;
    }
  }
  if (blockIdx.x == 0 && threadIdx.x == 0) offs[N] = totals[rel];
}

__global__ __launch_bounds__(256) void csr_scatter(
    const int* __restrict__ dst, const int* __restrict__ src,
    const bf16* __restrict__ ew, int E, int* __restrict__ cur,
    int* __restrict__ srcs, bf16* __restrict__ ews)
{
  const int i = blockIdx.x * 256 + threadIdx.x;
  if (i >= E) return;
  const int p = atomicAdd(&cur[dst[i]], 1);
  srcs[p] = src[i];
  ews[p]  = ew[i];
}

// -------------------------------------------------------------------------
// Fold per-head w_att/w_msg into K/M projections; emit fused-transposed
// KMT[l,e][512][256] bf16 + bias kmb[l,e][512]. grid (8, 24).
// -------------------------------------------------------------------------
__global__ __launch_bounds__(256) void combine_weights(
    const bf16* __restrict__ Wbig, const bf16* __restrict__ bbig,
    const bf16* __restrict__ wsm, bf16* __restrict__ KMT,
    bf16* __restrict__ kmb, int noff)
{
  const int blk = blockIdx.y;
  const int rc  = blockIdx.x;
  const int h = blk & 3;
  const int le = blk >> 2;
  const int e = le % 3;
  const int l = le / 3;
  const int st = (e == 1) ? 0 : 1;

  const short* Wsrc = (const short*)(Wbig + (size_t)(l * 2 + st) * 65536);
  const bf16*  bsrc = bbig + (size_t)(l * 2 + st) * 256;
  const short* wm   = (const short*)(wsm + ((size_t)(l * 3 + e) * 4 + h) * 4096);
  short* outT = (short*)(KMT + (size_t)(l * 3 + e) * 512 * 256);
  bf16* outb  = kmb + (size_t)(l * 3 + e) * 512;

  __shared__ short w[64][72];
  __shared__ short As[32][72];
  __shared__ short ot[64][40];

  const int t = threadIdx.x;
  {
    const int base = t * 16;
    const int r0 = base >> 6, c0 = base & 63;
    *(short8*)&w[r0][c0]     = *(const short8*)&wm[base];
    *(short8*)&w[r0][c0 + 8] = *(const short8*)&wm[base + 8];
  }
  {
    const int row = t >> 3;
    const int kc = (t & 7) * 8;
    *(short8*)&As[row][kc] =
        *(const short8*)&Wsrc[(size_t)(rc * 32 + row) * 256 + h * 64 + kc];
  }
  __syncthreads();

  const int j   = t & 63;
  const int sub = t >> 6;
  float accv[8] = {};
  #pragma unroll
  for (int d = 0; d < 64; ++d) {
    const float wd = bits2f((unsigned short)w[d][j]);
    #pragma unroll
    for (int r8 = 0; r8 < 8; ++r8)
      accv[r8] += bits2f((unsigned short)As[sub * 8 + r8][d]) * wd;
  }
  #pragma unroll
  for (int r8 = 0; r8 < 8; ++r8) {
    union { bf16 h; short s; } cv;
    cv.h = __float2bfloat16(accv[r8]);
    ot[j][sub * 8 + r8] = cv.s;
  }

  if (rc == 0 && t < 64) {
    float acc = 0.f;
    #pragma unroll
    for (int d = 0; d < 64; ++d)
      acc += toF(bsrc[h * 64 + d]) * bits2f((unsigned short)w[d][t]);
    outb[h * 64 + t + noff] = __float2bfloat16(acc);
  }
  __syncthreads();
  {
    const int nn = t >> 2;
    const int kx = (t & 3) * 8;
    short8 v;
    #pragma unroll
    for (int x = 0; x < 8; ++x) v[x] = ot[nn][kx + x];
    *(short8*)&outT[(size_t)(h * 64 + nn + noff) * 256 + rc * 32 + kx] = v;
  }
}

// -------------------------------------------------------------------------
// Multi-output MFMA GEMM. Tile 128(M) x 128(N), BK=64, 4 waves in 2x2.
// XCD-aware swizzle: blocks sharing an A-tile are 8 apart in dispatch order
// so round-robin XCD assignment puts them on ONE XCD -> A re-reads hit L2.
// -------------------------------------------------------------------------
__global__ __launch_bounds__(256, 4) void mfma_gemm128(
    const void* __restrict__ A, const unsigned* __restrict__ aflag,
    MultiDesc md, int M, int ntiles, int nslab)
{
  __shared__ short As[128][72];
  __shared__ short Bs[128][72];
  const int lid = blockIdx.x;
  const int grp = lid / (8 * nslab);
  const int rem = lid - grp * 8 * nslab;
  const int slab = rem >> 3;
  const int tx = grp * 8 + (rem & 7);
  if (tx >= ntiles) return;
  const GemmDesc d = md.d[slab];
  const bool abf = (*aflag != 0u);
  const int t = threadIdx.x;
  const int bm = tx * 128;
  const int lane = t & 63;
  const int wid  = t >> 6;
  const int wm = (wid >> 1) * 64;
  const int wn = (wid & 1) * 64;
  const int col16 = lane & 15;
  const int quad  = lane >> 4;
  const int rr = t >> 3;
  const int kk = (t & 7) * 8;

  float4v acc[4][4];
  #pragma unroll
  for (int mi = 0; mi < 4; ++mi)
    #pragma unroll
    for (int ni = 0; ni < 4; ++ni) acc[mi][ni] = (float4v){0.f, 0.f, 0.f, 0.f};

  for (int k0 = 0; k0 < 256; k0 += 64) {
    #pragma unroll
    for (int it = 0; it < 4; ++it) {
      const int row = it * 32 + rr;
      const int grow = bm + row;
      short8 v = (short8){0, 0, 0, 0, 0, 0, 0, 0};
      if (grow < M) {
        if (abf) {
          v = *(const short8*)((const short*)A + (size_t)grow * 256 + k0 + kk);
        } else {
          const float* ap = (const float*)A + (size_t)grow * 256 + k0 + kk;
          #pragma unroll
          for (int j = 0; j < 8; ++j) {
            union { bf16 h; short s; } cv;
            cv.h = __float2bfloat16(ap[j]);
            v[j] = cv.s;
          }
        }
      }
      *(short8*)&As[row][kk] = v;
    }
    #pragma unroll
    for (int it = 0; it < 4; ++it) {
      const int n = it * 32 + rr;
      *(short8*)&Bs[n][kk] = *(const short8*)&d.wt[(size_t)n * 256 + k0 + kk];
    }
    __syncthreads();

    #pragma unroll
    for (int ks = 0; ks < 64; ks += 32) {
      short8 bfr[4];
      #pragma unroll
      for (int ni = 0; ni < 4; ++ni)
        bfr[ni] = *(const short8*)&Bs[wn + ni * 16 + col16][ks + quad * 8];
      #pragma unroll
      for (int mi = 0; mi < 4; ++mi) {
        const short8 afr = *(const short8*)&As[wm + mi * 16 + col16][ks + quad * 8];
        #pragma unroll
        for (int ni = 0; ni < 4; ++ni)
          acc[mi][ni] = __builtin_amdgcn_mfma_f32_16x16x32_bf16(afr, bfr[ni], acc[mi][ni], 0, 0, 0);
      }
    }
    __syncthreads();
  }

  #pragma unroll
  for (int ni = 0; ni < 4; ++ni) {
    const int col = wn + ni * 16 + col16;
    const float bc = toF(d.bias[col]);
    const int gcol = d.coff + col;
    #pragma unroll
    for (int mi = 0; mi < 4; ++mi) {
      #pragma unroll
      for (int r = 0; r < 4; ++r) {
        const int row = bm + wm + mi * 16 + quad * 4 + r;
        if (row < M) {
          float v = acc[mi][ni][r] + bc;
          if (d.act == 1) v = gelu_exact(v);
          const size_t idx = (size_t)row * d.ldc + gcol;
          if (d.otype == 0) ((bf16*)d.c)[idx] = __float2bfloat16(v);
          else              ((float*)d.c)[idx] = v;
        }
      }
    }
  }
}

// -------------------------------------------------------------------------
// Fused A-projection + skip + LayerNorm. Block computes a full 128x256
// row-slab of tr = A@W + b (2 col-slabs looped, acc in 128 VGPRs), then:
// o = tr*alpha + feat*(1-alpha); feat = bf16(LN(o)*g + bvec). In-place.
// LDS 57.3 KB -> 2 blocks/CU.
// -------------------------------------------------------------------------
__global__ __launch_bounds__(256, 2) void mfma_gemm_ln(
    const bf16* __restrict__ A, const short* __restrict__ WT,
    const bf16* __restrict__ bias, bf16* __restrict__ feat,
    const bf16* __restrict__ skipv, const bf16* __restrict__ g,
    const bf16* __restrict__ bvec, int M)
{
  __shared__ short As[128][72];
  __shared__ short Bs[256][72];
  __shared__ float redS[4][64];
  __shared__ float redQ[4][64];
  const int t = threadIdx.x;
  const int bm = blockIdx.x * 128;
  const int lane = t & 63;
  const int wid  = t >> 6;
  const int wm = (wid >> 1) * 64;
  const int wn = (wid & 1) * 64;
  const int col16 = lane & 15;
  const int quad  = lane >> 4;
  const int rr = t >> 3;
  const int kk = (t & 7) * 8;

  float4v acc[2][4][4];
  #pragma unroll
  for (int s = 0; s < 2; ++s)
    #pragma unroll
    for (int mi = 0; mi < 4; ++mi)
      #pragma unroll
      for (int ni = 0; ni < 4; ++ni) acc[s][mi][ni] = (float4v){0.f, 0.f, 0.f, 0.f};

  for (int k0 = 0; k0 < 256; k0 += 64) {
    #pragma unroll
    for (int it = 0; it < 4; ++it) {
      const int row = it * 32 + rr;
      const int grow = bm + row;
      short8 v = (short8){0, 0, 0, 0, 0, 0, 0, 0};
      if (grow < M)
        v = *(const short8*)((const short*)A + (size_t)grow * 256 + k0 + kk);
      *(short8*)&As[row][kk] = v;
    }
    #pragma unroll
    for (int it = 0; it < 8; ++it) {
      const int n = it * 32 + rr;
      *(short8*)&Bs[n][kk] = *(const short8*)&WT[(size_t)n * 256 + k0 + kk];
    }
    __syncthreads();

    #pragma unroll
    for (int ks = 0; ks < 64; ks += 32) {
      short8 bfr[2][4];
      #pragma unroll
      for (int s = 0; s < 2; ++s)
        #pragma unroll
        for (int ni = 0; ni < 4; ++ni)
          bfr[s][ni] = *(const short8*)&Bs[s * 128 + wn + ni * 16 + col16][ks + quad * 8];
      #pragma unroll
      for (int mi = 0; mi < 4; ++mi) {
        const short8 afr = *(const short8*)&As[wm + mi * 16 + col16][ks + quad * 8];
        #pragma unroll
        for (int s = 0; s < 2; ++s)
          #pragma unroll
          for (int ni = 0; ni < 4; ++ni)
            acc[s][mi][ni] = __builtin_amdgcn_mfma_f32_16x16x32_bf16(afr, bfr[s][ni], acc[s][mi][ni], 0, 0, 0);
      }
    }
    __syncthreads();
  }

  // ---- epilogue: blend + LN ----
  const float alpha = sigmoidf_(toF(*skipv));
  const float beta = 1.f - alpha;
  float ps[4][4] = {};
  float pq[4][4] = {};
  #pragma unroll
  for (int s = 0; s < 2; ++s) {
    #pragma unroll
    for (int ni = 0; ni < 4; ++ni) {
      const int col = wn + s * 128 + ni * 16 + col16;
      const float bc = toF(bias[col]);
      #pragma unroll
      for (int mi = 0; mi < 4; ++mi) {
        #pragma unroll
        for (int rg = 0; rg < 4; ++rg) {
          const int row = bm + wm + mi * 16 + quad * 4 + rg;
          float f = 0.f;
          if (row < M) f = toF(feat[(size_t)row * 256 + col]);
          const float o = (acc[s][mi][ni][rg] + bc) * alpha + f * beta;
          acc[s][mi][ni][rg] = o;
          ps[mi][rg] += o;
          pq[mi][rg] += o * o;
        }
      }
    }
  }
  // reduce across the 16-lane col16 group
  #pragma unroll
  for (int mi = 0; mi < 4; ++mi)
    #pragma unroll
    for (int rg = 0; rg < 4; ++rg) {
      #pragma unroll
      for (int off = 1; off < 16; off <<= 1) {
        ps[mi][rg] += __shfl_xor(ps[mi][rg], off);
        pq[mi][rg] += __shfl_xor(pq[mi][rg], off);
      }
    }
  if (col16 == 0) {
    #pragma unroll
    for (int mi = 0; mi < 4; ++mi)
      #pragma unroll
      for (int rg = 0; rg < 4; ++rg) {
        const int rl = mi * 16 + quad * 4 + rg;
        redS[wid][rl] = ps[mi][rg];
        redQ[wid][rl] = pq[mi][rg];
      }
  }
  __syncthreads();
  const int pbase = (wid >> 1) * 2;
  #pragma unroll
  for (int mi = 0; mi < 4; ++mi) {
    #pragma unroll
    for (int rg = 0; rg < 4; ++rg) {
      const int rl = mi * 16 + quad * 4 + rg;
      const float s1 = redS[pbase][rl] + redS[pbase + 1][rl];
      const float s2 = redQ[pbase][rl] + redQ[pbase + 1][rl];
      const float mu = s1 * (1.f / 256.f);
      float var = s2 * (1.f / 256.f) - mu * mu;
      var = fmaxf(var, 0.f);
      const float rs = rsqrtf(var + 1e-5f);
      const int row = bm + wm + mi * 16 + quad * 4 + rg;
      if (row < M) {
        #pragma unroll
        for (int s = 0; s < 2; ++s)
          #pragma unroll
          for (int ni = 0; ni < 4; ++ni) {
            const int col = wn + s * 128 + ni * 16 + col16;
            const float r = (acc[s][mi][ni][rg] - mu) * rs * toF(g[col]) + toF(bvec[col]);
            feat[(size_t)row * 256 + col] = __float2bfloat16(r);
          }
      }
    }
  }
}

// -------------------------------------------------------------------------
// CSR gather v2: one wave per dst node, split into two 32-lane halves over
// alternate edges; 16B loads; 3-round 8-lane head reduction.
// -------------------------------------------------------------------------
__global__ __launch_bounds__(256) void gather_kernel(
    const bf16* __restrict__ q, const bf16* __restrict__ km,
    const int* __restrict__ srcs, const bf16* __restrict__ ews,
    const int* __restrict__ offs, const bf16* __restrict__ pri,
    bf16* __restrict__ agg, int Nd, int addPrev, float finalScale)
{
  const int lane = threadIdx.x & 63;
  const int wid  = threadIdx.x >> 6;
  const int node = blockIdx.x * 4 + wid;
  if (node >= Nd) return;
  const int h  = lane >> 5;
  const int sl = lane & 31;
  const float prih = toF(pri[sl >> 3]);

  union B8 { uint4 u; unsigned short s[8]; };
  B8 qv;
  qv.u = ((const uint4*)(q + (size_t)node * 256))[sl];
  float qf[8];
  #pragma unroll
  for (int j = 0; j < 8; ++j) qf[j] = bits2f(qv.s[j]);

  float acc[8] = {};
  const int beg = offs[node], end = offs[node + 1];
  for (int idx = beg + h; idx < end; idx += 2) {
    const int s = srcs[idx];
    const float w = toF(ews[idx]);
    B8 kb;
    kb.u = ((const uint4*)(km + (size_t)s * 512))[sl];
    float dot = 0.f;
    #pragma unroll
    for (int j = 0; j < 8; ++j) dot += qf[j] * bits2f(kb.s[j]);
    dot += __shfl_xor(dot, 1);
    dot += __shfl_xor(dot, 2);
    dot += __shfl_xor(dot, 4);
    const float a = w * sigmoidf_(dot * prih * 0.125f);
    B8 mb;
    mb.u = ((const uint4*)(km + (size_t)s * 512 + 256))[sl];
    #pragma unroll
    for (int j = 0; j < 8; ++j) acc[j] += bits2f(mb.s[j]) * a;
  }

  #pragma unroll
  for (int j = 0; j < 8; ++j) acc[j] += __shfl_xor(acc[j], 32);

  if (h == 0) {
    bf16* out = agg + (size_t)node * 256 + sl * 8;
    if (addPrev) {
      B8 pb;
      pb.u = *(const uint4*)out;
      #pragma unroll
      for (int j = 0; j < 8; ++j) acc[j] += bits2f(pb.s[j]);
    }
    B8 ov;
    #pragma unroll
    for (int j = 0; j < 8; ++j) {
      union { bf16 h; unsigned short u; } cv;
      cv.h = __float2bfloat16(acc[j] * finalScale);
      ov.s[j] = cv.u;
    }
    *(uint4*)out = ov.u;
  }
}

// -------------------------------------------------------------------------
// out[M,64] = A[M,256] @ W[256,64] + b[64]; output dtype per *flag.
// -------------------------------------------------------------------------
__global__ __launch_bounds__(256) void out_gemm(
    const bf16* __restrict__ A, const bf16* __restrict__ W,
    const bf16* __restrict__ bias, void* __restrict__ out,
    const unsigned* __restrict__ flag, int M)
{
  __shared__ float Ws[64][64];
  const bool obf = (*flag != 0u);
  const int tid = threadIdx.x;
  const int row = blockIdx.x * 64 + (tid >> 2);
  const int c0 = (tid & 3) * 16;
  const int arow = (row < M) ? row : 0;
  const bf16* a = A + (size_t)arow * 256;
  float acc[16] = {};
  for (int k0 = 0; k0 < 256; k0 += 64) {
    for (int i = tid; i < 4096; i += 256)
      Ws[i >> 6][i & 63] = toF(W[(size_t)(k0 + (i >> 6)) * 64 + (i & 63)]);
    __syncthreads();
    for (int k = 0; k < 64; ++k) {
      const float av = toF(a[k0 + k]);
      #pragma unroll
      for (int j = 0; j < 16; ++j) acc[j] += av * Ws[k][c0 + j];
    }
    __syncthreads();
  }
  if (row < M) {
    #pragma unroll
    for (int j = 0; j < 16; ++j) {
      const float v = acc[j] + toF(bias[c0 + j]);
      const size_t idx = (size_t)row * 64 + c0 + j;
      if (obf) ((bf16*)out)[idx] = __float2bfloat16(v);
      else     ((float*)out)[idx] = v;
    }
  }
}

// -------------------------------------------------------------------------
extern "C" void kernel_launch(void* const* d_in, const int* in_sizes, int n_in,
                              void* d_out, int out_size, void* d_ws, size_t ws_size,
                              hipStream_t stream) {
  const int* src_wb  = (const int*)d_in[23];
  const int* dst_wb  = (const int*)d_in[24];
  const int* src_w   = (const int*)d_in[25];
  const int* dst_w   = (const int*)d_in[26];
  const int* src_c   = (const int*)d_in[27];
  const int* dst_c   = (const int*)d_in[28];

  // ---- workspace carve (~166 MB total) ----
  char* base = (char*)d_ws;
  unsigned* flags = (unsigned*)base;                       // 256 B
  bf16* canon = (bf16*)(base + 256);
  char* p = base + 256 + (((size_t)kCanonTotal * 2 + 511) & ~(size_t)511);
  bf16* adWT = (bf16*)p;                     // 2 x 65536
  bf16* qWT  = adWT + (size_t)2 * 65536;     // 4 x 65536
  bf16* aWT  = qWT  + (size_t)4 * 65536;     // 4 x 65536
  bf16* KMeffT = aWT + (size_t)4 * 65536;    // 6 x 512*256
  bf16* kmbeT  = KMeffT + (size_t)6 * 512 * 256;  // 6 x 512
  char* pc = (char*)(((size_t)(kmbeT + 6 * 512) + 511) & ~(size_t)511);
  // CSR region
  int* cur_wb  = (int*)pc;
  int* cur_w   = cur_wb + (kNA + 1);
  int* cur_c   = cur_w + (kNP + 1);
  int* offs_wb = cur_c + (kNP + 1);
  int* offs_w  = offs_wb + (kNA + 1);
  int* offs_c  = offs_w + (kNP + 1);
  int* srcs_wb = offs_c + (kNP + 1);
  int* srcs_w  = srcs_wb + kEWB;
  int* srcs_c  = srcs_w + kEW;
  bf16* ews_wb = (bf16*)(srcs_c + kEC);
  bf16* ews_w  = ews_wb + kEWB;
  bf16* ews_c  = ews_w + kEW;
  int* bsums   = (int*)(ews_c + kEC);     // [3][32]
  int* totals  = bsums + 96;              // [3]
  char* p2 = (char*)(((size_t)(totals + 3) + 511) & ~(size_t)511);
  bf16* fa  = (bf16*)p2;                  // [NA,256]
  bf16* fp_ = fa + (size_t)kNA * 256;     // [NP,256]
  char* R   = (char*)(fp_ + (size_t)kNP * 256);
  bf16* qa   = (bf16*)R;                  // [NA,256]
  bf16* qp   = qa + (size_t)kNA * 256;    // [NP,256]
  bf16* km_a = qp + (size_t)kNP * 256;    // [NA,512]
  bf16* km_p = km_a + (size_t)kNA * 512;  // [NP,512]
  char* afterR = R + ((size_t)(kNA + kNP) * 256 + (size_t)(kNA + kNP) * 512) * sizeof(bf16);
  bf16* agg_a = (bf16*)afterR;            // [NA,256]
  bf16* agg_p = agg_a + (size_t)kNA * 256;// [NP,256]

  const bf16* c_ew_wb = canon + kOff(0);
  const bf16* c_ew_w  = canon + kOff(1);
  const bf16* c_ew_c  = canon + kOff(2);
  const bf16* c_adW   = canon + kOff(3);
  const bf16* c_adb   = canon + kOff(4);
  const bf16* c_kW    = canon + kOff(5);
  const bf16* c_kb    = canon + kOff(6);
  const bf16* c_qW    = canon + kOff(7);
  const bf16* c_qb    = canon + kOff(8);
  const bf16* c_mW    = canon + kOff(9);
  const bf16* c_mb    = canon + kOff(10);
  const bf16* c_aW    = canon + kOff(11);
  const bf16* c_ab    = canon + kOff(12);
  const bf16* c_wpri  = canon + kOff(13);
  const bf16* c_watt  = canon + kOff(14);
  const bf16* c_wmsg  = canon + kOff(15);
  const bf16* c_skip  = canon + kOff(16);
  const bf16* c_lng   = canon + kOff(17);
  const bf16* c_lnb   = canon + kOff(18);
  const bf16* c_outW  = canon + kOff(19);
  const bf16* c_outb  = canon + kOff(20);

  const unsigned* fIn = flags + 0;
  const unsigned* f1  = flags + 1;

  detect_dtype<<<1, 256, 0, stream>>>((const unsigned*)d_in[0], flags);

  CanonArgs ca;
  for (int s = 0; s < kNSeg; ++s) { ca.n[s] = kSegN[s]; ca.dstOff[s] = (unsigned)kOff(s); }
  const int srcIdx[kNSeg] = {2,3,4, 5,6, 7,8, 9,10, 11,12, 13,14, 15, 16,17, 18,19,20, 21,22};
  for (int s = 0; s < kNSeg; ++s) ca.src[s] = d_in[srcIdx[s]];
  canon_kernel<<<dim3(1172, kNSeg), 256, 0, stream>>>(ca, canon, flags);

  // ---- transpose the 10 dense 256x256 weights into [n][k] layout ----
  TransArgs ta;
  ta.src[0] = c_adW;              ta.dst[0] = adWT;
  ta.src[1] = c_adW + 65536;      ta.dst[1] = adWT + 65536;
  for (int m = 0; m < 4; ++m) { ta.src[2 + m] = c_qW + (size_t)m * 65536; ta.dst[2 + m] = qWT + (size_t)m * 65536; }
  for (int m = 0; m < 4; ++m) { ta.src[6 + m] = c_aW + (size_t)m * 65536; ta.dst[6 + m] = aWT + (size_t)m * 65536; }
  transpose_w<<<dim3(4, 4, 10), 256, 0, stream>>>(ta);

  // ---- CSR build ----
  hipMemsetAsync(cur_wb, 0, (size_t)((kNA + 1) + 2 * (kNP + 1)) * 4, stream);
  csr_hist<<<(kEWB + 255) / 256, 256, 0, stream>>>(dst_wb, kEWB, cur_wb);
  csr_hist<<<(kEW  + 255) / 256, 256, 0, stream>>>(dst_w,  kEW,  cur_w);
  csr_hist<<<(kEC  + 255) / 256, 256, 0, stream>>>(dst_c,  kEC,  cur_c);
  ScanArgs sa;
  sa.deg[0] = cur_wb;  sa.offs[0] = offs_wb; sa.N[0] = kNA;
  sa.deg[1] = cur_w;   sa.offs[1] = offs_w;  sa.N[1] = kNP;
  sa.deg[2] = cur_c;   sa.offs[2] = offs_c;  sa.N[2] = kNP;
  sa.bsums = bsums;
  scan_l1<<<dim3(32, 3), 256, 0, stream>>>(sa);
  scan_l2<<<3, 64, 0, stream>>>(bsums, totals);
  scan_l3<<<dim3(20, 3), 256, 0, stream>>>(sa, totals);
  csr_scatter<<<(kEWB + 255) / 256, 256, 0, stream>>>(dst_wb, src_wb, c_ew_wb, kEWB, cur_wb, srcs_wb, ews_wb);
  csr_scatter<<<(kEW  + 255) / 256, 256, 0, stream>>>(dst_w,  src_w,  c_ew_w,  kEW,  cur_w,  srcs_w,  ews_w);
  csr_scatter<<<(kEC  + 255) / 256, 256, 0, stream>>>(dst_c,  src_c,  c_ew_c,  kEC,  cur_c,  srcs_c,  ews_c);

  // fused K|M effective weights (K: noff=0, M: noff=256)
  combine_weights<<<dim3(8, 24), 256, 0, stream>>>(c_kW, c_kb, c_watt, KMeffT, kmbeT, 0);
  combine_weights<<<dim3(8, 24), 256, 0, stream>>>(c_mW, c_mb, c_wmsg, KMeffT, kmbeT, 256);

  auto sgrid = [](int m, int nslab) {
    const int nt = (m + 127) / 128;
    return dim3((unsigned)(((nt + 7) / 8) * 8 * nslab));
  };
  auto ntl = [](int m) { return (m + 127) / 128; };
  auto mkd = [](const bf16* wt, const bf16* bias, void* c, int ldc, int coff,
                int act, int otype) {
    GemmDesc g;
    g.wt = (const short*)wt; g.bias = bias; g.c = c; g.ldc = ldc;
    g.coff = coff; g.act = act; g.otype = otype; g.pad = 0;
    return g;
  };

  // adapt: feats = gelu(x @ adapt_W + adapt_b)
  {
    MultiDesc md{};
    md.d[0] = mkd(adWT,                c_adb,        fa, 256, 0,   1, 0);
    md.d[1] = mkd(adWT + 128 * 256,    c_adb + 128,  fa, 256, 128, 1, 0);
    mfma_gemm128<<<sgrid(kNA, 2), 256, 0, stream>>>(d_in[0], fIn, md, kNA, ntl(kNA), 2);
    md.d[0] = mkd(adWT + 65536,        c_adb + 256,  fp_, 256, 0,   1, 0);
    md.d[1] = mkd(adWT + 65536 + 128 * 256, c_adb + 384, fp_, 256, 128, 1, 0);
    mfma_gemm128<<<sgrid(kNP, 2), 256, 0, stream>>>(d_in[1], fIn, md, kNP, ntl(kNP), 2);
  }

  for (int l = 0; l < 2; ++l) {
    const bf16* qW_a = qWT + (size_t)(l * 2 + 0) * 65536;
    const bf16* qW_p = qWT + (size_t)(l * 2 + 1) * 65536;
    const bf16* qb_a = c_qb + (l * 2 + 0) * 256;
    const bf16* qb_p = c_qb + (l * 2 + 1) * 256;
    const bf16* KM_c  = KMeffT + (size_t)(l * 3 + 0) * 512 * 256;
    const bf16* KM_w  = KMeffT + (size_t)(l * 3 + 1) * 512 * 256;
    const bf16* KM_wb = KMeffT + (size_t)(l * 3 + 2) * 512 * 256;
    const bf16* kb_c  = kmbeT + (l * 3 + 0) * 512;
    const bf16* kb_w  = kmbeT + (l * 3 + 1) * 512;
    const bf16* kb_wb = kmbeT + (l * 3 + 2) * 512;

    // authors-proj: Q_a (2 slabs) + KM_w (4 slabs) from fa
    {
      MultiDesc md{};
      md.d[0] = mkd(qW_a,             qb_a,        qa,   256, 0,   0, 0);
      md.d[1] = mkd(qW_a + 128 * 256, qb_a + 128,  qa,   256, 128, 0, 0);
      for (int s = 0; s < 4; ++s)
        md.d[2 + s] = mkd(KM_w + (size_t)s * 128 * 256, kb_w + s * 128, km_a, 512, s * 128, 0, 0);
      mfma_gemm128<<<sgrid(kNA, 6), 256, 0, stream>>>(fa, f1, md, kNA, ntl(kNA), 6);
    }
    // papers-proj: Q_p (2 slabs) + KM_wb (4 slabs) from fp_
    {
      MultiDesc md{};
      md.d[0] = mkd(qW_p,             qb_p,        qp,   256, 0,   0, 0);
      md.d[1] = mkd(qW_p + 128 * 256, qb_p + 128,  qp,   256, 128, 0, 0);
      for (int s = 0; s < 4; ++s)
        md.d[2 + s] = mkd(KM_wb + (size_t)s * 128 * 256, kb_wb + s * 128, km_p, 512, s * 128, 0, 0);
      mfma_gemm128<<<sgrid(kNP, 6), 256, 0, stream>>>(fp_, f1, md, kNP, ntl(kNP), 6);
    }

    // WRITTEN_BY: paper -> author
    gather_kernel<<<(kNA + 3) / 4, 256, 0, stream>>>(
        qa, km_p, srcs_wb, ews_wb, offs_wb, c_wpri + (l * 3 + 2) * 4,
        agg_a, kNA, 0, 1.f);
    // WRITES: author -> paper
    gather_kernel<<<(kNP + 3) / 4, 256, 0, stream>>>(
        qp, km_a, srcs_w, ews_w, offs_w, c_wpri + (l * 3 + 1) * 4,
        agg_p, kNP, 0, 1.f);

    // cites-KM: reuse km_p (wb gather already done in stream order)
    {
      MultiDesc md{};
      for (int s = 0; s < 4; ++s)
        md.d[s] = mkd(KM_c + (size_t)s * 128 * 256, kb_c + s * 128, km_p, 512, s * 128, 0, 0);
      mfma_gemm128<<<sgrid(kNP, 4), 256, 0, stream>>>(fp_, f1, md, kNP, ntl(kNP), 4);
    }
    // CITES: paper -> paper, chained add + 0.5 mean
    gather_kernel<<<(kNP + 3) / 4, 256, 0, stream>>>(
        qp, km_p, srcs_c, ews_c, offs_c, c_wpri + (l * 3 + 0) * 4,
        agg_p, kNP, 1, 0.5f);

    // fused A-projection + skip + LayerNorm, in-place on feats
    mfma_gemm_ln<<<ntl(kNA), 256, 0, stream>>>(
        agg_a, (const short*)(aWT + (size_t)(l * 2 + 0) * 65536),
        c_ab + (l * 2 + 0) * 256, fa, c_skip + l * 3 + 0,
        c_lng + (l * 2 + 0) * 256, c_lnb + (l * 2 + 0) * 256, kNA);
    mfma_gemm_ln<<<ntl(kNP), 256, 0, stream>>>(
        agg_p, (const short*)(aWT + (size_t)(l * 2 + 1) * 65536),
        c_ab + (l * 2 + 1) * 256, fp_, c_skip + l * 3 + 1,
        c_lng + (l * 2 + 1) * 256, c_lnb + (l * 2 + 1) * 256, kNP);
  }

  out_gemm<<<kNP / 64, 256, 0, stream>>>(fp_, c_outW, c_outb, d_out, fIn, kNP);
}

// Round 11
// 904.806 us; speedup vs baseline: 1.1509x; 1.1509x over previous
//
#include <hip/hip_runtime.h>
#include <hip/hip_bf16.h>
#include <math.h>

using bf16 = __hip_bfloat16;

typedef __attribute__((ext_vector_type(8))) short short8;   // 8 bf16 (4 VGPRs)
typedef __attribute__((ext_vector_type(4))) float float4v;  // MFMA acc

static constexpr int kNA  = 20000;
static constexpr int kNP  = 40000;
static constexpr int kEWB = 150000;
static constexpr int kEW  = 150000;
static constexpr int kEC  = 300000;

// ---- canonical bf16 input region ----
static constexpr int kNSeg = 21;
static constexpr int kSegN[kNSeg] = {
  150000, 150000, 300000,           // ew_wb, ew_w, ew_c
  131072, 512,                      // adW, adb
  262144, 1024,                     // kW, kb
  262144, 1024,                     // qW, qb
  262144, 1024,                     // mW, mb
  262144, 1024,                     // aW, ab
  24,                               // wpri
  98304, 98304,                     // watt, wmsg
  6, 1024, 1024,                    // skip, lng, lnb
  16384, 64                         // outW, outb
};
static constexpr size_t kOff(int s) {
  size_t o = 0;
  for (int i = 0; i < s; ++i) o += (size_t)kSegN[i];
  return o;
}
static constexpr size_t kCanonTotal = kOff(kNSeg);

struct CanonArgs {
  const void* src[kNSeg];
  int n[kNSeg];
  unsigned dstOff[kNSeg];
};
struct TransArgs {
  const bf16* src[10];
  bf16* dst[10];
};
// per-slab GEMM output descriptor (slab = 128 output cols)
struct GemmDesc {
  const short* wt;   // [128][256] n-major slab
  const bf16* bias;  // 128 entries (slab-local)
  void* c;           // output base
  int ldc;           // in elements
  int coff;          // global col offset of this slab in C
  int act;           // 1 = gelu
  int otype;         // 0 = bf16, 1 = fp32
  int pad;
};
struct MultiDesc { GemmDesc d[6]; };
// three-relation scan descriptor
struct ScanArgs {
  int* deg[3];   // degree arrays (also cursor output)
  int* offs[3];  // offsets (N+1)
  int* bsums;    // [3][32] block sums
  int N[3];
};

__device__ __forceinline__ float toF(float x) { return x; }
__device__ __forceinline__ float toF(bf16 x)  { return __bfloat162float(x); }
__device__ __forceinline__ float bits2f(unsigned short b) {
  unsigned int u = ((unsigned int)b) << 16;
  return __uint_as_float(u);
}
__device__ __forceinline__ float sigmoidf_(float x) { return 1.0f / (1.0f + expf(-x)); }
__device__ __forceinline__ float gelu_exact(float x) {
  return 0.5f * x * (1.0f + erff(x * 0.70710678118654752f));
}

// -------------------------------------------------------------------------
// Input-dtype sniffer. flags: [0]=isBf16 [1]=1
// -------------------------------------------------------------------------
__global__ __launch_bounds__(256) void detect_dtype(
    const unsigned* __restrict__ x, unsigned* __restrict__ flags)
{
  __shared__ int cnt;
  if (threadIdx.x == 0) cnt = 0;
  __syncthreads();
  unsigned w = x[threadIdx.x];
  unsigned e = (w >> 7) & 0xFFu;
  if (e >= 110u && e <= 140u) atomicAdd(&cnt, 1);
  __syncthreads();
  if (threadIdx.x == 0) {
    flags[0] = (cnt >= 128) ? 1u : 0u;
    flags[1] = 1u;
  }
}

__global__ __launch_bounds__(256) void canon_kernel(
    CanonArgs a, bf16* __restrict__ dst, const unsigned* __restrict__ flags)
{
  const int s = blockIdx.y;
  const int i = blockIdx.x * 256 + threadIdx.x;
  if (i >= a.n[s]) return;
  bf16 v;
  if (flags[0]) v = ((const bf16*)a.src[s])[i];
  else          v = __float2bfloat16(((const float*)a.src[s])[i]);
  dst[a.dstOff[s] + i] = v;
}

// -------------------------------------------------------------------------
// Batched 256x256 weight transpose: dst[n][k] = src[k][n]. grid (4,4,10).
// -------------------------------------------------------------------------
__global__ __launch_bounds__(256) void transpose_w(TransArgs ta)
{
  const int m = blockIdx.z;
  const short* src = (const short*)ta.src[m];
  short* dst = (short*)ta.dst[m];
  const int k0 = blockIdx.x * 64, n0 = blockIdx.y * 64;
  __shared__ short tile[64][65];
  const int tx = threadIdx.x & 63, ty = threadIdx.x >> 6;
  for (int i = ty; i < 64; i += 4)
    tile[i][tx] = src[(size_t)(k0 + i) * 256 + n0 + tx];
  __syncthreads();
  for (int i = ty; i < 64; i += 4)
    dst[(size_t)(n0 + i) * 256 + k0 + tx] = tile[tx][i];
}

// -------------------------------------------------------------------------
// CSR build: histogram -> 3-level parallel scan -> gather-scatter.
// -------------------------------------------------------------------------
__global__ __launch_bounds__(256) void csr_hist(
    const int* __restrict__ dst, int E, int* __restrict__ cnt)
{
  const int i = blockIdx.x * 256 + threadIdx.x;
  if (i < E) atomicAdd(&cnt[dst[i]], 1);
}

__global__ __launch_bounds__(256) void scan_l1(ScanArgs a)
{
  const int rel = blockIdx.y;
  const int N = a.N[rel];
  const int t = threadIdx.x;
  const int lane = t & 63;
  const int wid = t >> 6;
  const int i0 = blockIdx.x * 2048 + t * 8;
  const int* deg = a.deg[rel];
  int v[8];
  int T = 0;
  #pragma unroll
  for (int j = 0; j < 8; ++j) {
    v[j] = (i0 + j < N) ? deg[i0 + j] : 0;
    T += v[j];
  }
  int incl = T;
  #pragma unroll
  for (int off = 1; off < 64; off <<= 1) {
    const int u = __shfl_up(incl, off);
    if (lane >= off) incl += u;
  }
  __shared__ int wsum[4];
  if (lane == 63) wsum[wid] = incl;
  __syncthreads();
  int woff = 0;
  #pragma unroll
  for (int wp = 0; wp < 4; ++wp) if (wp < wid) woff += wsum[wp];
  int run = woff + incl - T;
  int* offs = a.offs[rel];
  #pragma unroll
  for (int j = 0; j < 8; ++j) {
    if (i0 + j < N) offs[i0 + j] = run;
    run += v[j];
  }
  if (t == 0)
    a.bsums[rel * 32 + blockIdx.x] = wsum[0] + wsum[1] + wsum[2] + wsum[3];
}

__global__ __launch_bounds__(64) void scan_l2(int* __restrict__ bsums,
                                              int* __restrict__ totals)
{
  const int rel = blockIdx.x;
  const int lane = threadIdx.x;
  const int v = (lane < 32) ? bsums[rel * 32 + lane] : 0;
  int incl = v;
  #pragma unroll
  for (int off = 1; off < 64; off <<= 1) {
    const int u = __shfl_up(incl, off);
    if (lane >= off) incl += u;
  }
  if (lane < 32) bsums[rel * 32 + lane] = incl - v;
  if (lane == 63) totals[rel] = incl;
}

__global__ __launch_bounds__(256) void scan_l3(ScanArgs a,
                                               const int* __restrict__ totals)
{
  const int rel = blockIdx.y;
  const int N = a.N[rel];
  const int i0 = blockIdx.x * 2048 + threadIdx.x * 8;
  const int boff = a.bsums[rel * 32 + blockIdx.x];
  int* offs = a.offs[rel];
  int* cur = a.deg[rel];
  #pragma unroll
  for (int j = 0; j < 8; ++j) {
    const int idx = i0 + j;
    if (idx < N) {
      const int o = offs[idx] + boff;
      offs[idx] = o;
      cur[idx] = o;
    }
  }
  if (blockIdx.x == 0 && threadIdx.x == 0) offs[N] = totals[rel];
}

__global__ __launch_bounds__(256) void csr_scatter(
    const int* __restrict__ dst, const int* __restrict__ src,
    const bf16* __restrict__ ew, int E, int* __restrict__ cur,
    int* __restrict__ srcs, bf16* __restrict__ ews)
{
  const int i = blockIdx.x * 256 + threadIdx.x;
  if (i >= E) return;
  const int p = atomicAdd(&cur[dst[i]], 1);
  srcs[p] = src[i];
  ews[p]  = ew[i];
}

// -------------------------------------------------------------------------
// Fold per-head w_att/w_msg into K/M projections; emit fused-transposed
// KMT[l,e][512][256] bf16 + bias kmb[l,e][512]. grid (8, 24).
// -------------------------------------------------------------------------
__global__ __launch_bounds__(256) void combine_weights(
    const bf16* __restrict__ Wbig, const bf16* __restrict__ bbig,
    const bf16* __restrict__ wsm, bf16* __restrict__ KMT,
    bf16* __restrict__ kmb, int noff)
{
  const int blk = blockIdx.y;
  const int rc  = blockIdx.x;
  const int h = blk & 3;
  const int le = blk >> 2;
  const int e = le % 3;
  const int l = le / 3;
  const int st = (e == 1) ? 0 : 1;

  const short* Wsrc = (const short*)(Wbig + (size_t)(l * 2 + st) * 65536);
  const bf16*  bsrc = bbig + (size_t)(l * 2 + st) * 256;
  const short* wm   = (const short*)(wsm + ((size_t)(l * 3 + e) * 4 + h) * 4096);
  short* outT = (short*)(KMT + (size_t)(l * 3 + e) * 512 * 256);
  bf16* outb  = kmb + (size_t)(l * 3 + e) * 512;

  __shared__ short w[64][72];
  __shared__ short As[32][72];
  __shared__ short ot[64][40];

  const int t = threadIdx.x;
  {
    const int base = t * 16;
    const int r0 = base >> 6, c0 = base & 63;
    *(short8*)&w[r0][c0]     = *(const short8*)&wm[base];
    *(short8*)&w[r0][c0 + 8] = *(const short8*)&wm[base + 8];
  }
  {
    const int row = t >> 3;
    const int kc = (t & 7) * 8;
    *(short8*)&As[row][kc] =
        *(const short8*)&Wsrc[(size_t)(rc * 32 + row) * 256 + h * 64 + kc];
  }
  __syncthreads();

  const int j   = t & 63;
  const int sub = t >> 6;
  float accv[8] = {};
  #pragma unroll
  for (int d = 0; d < 64; ++d) {
    const float wd = bits2f((unsigned short)w[d][j]);
    #pragma unroll
    for (int r8 = 0; r8 < 8; ++r8)
      accv[r8] += bits2f((unsigned short)As[sub * 8 + r8][d]) * wd;
  }
  #pragma unroll
  for (int r8 = 0; r8 < 8; ++r8) {
    union { bf16 h; short s; } cv;
    cv.h = __float2bfloat16(accv[r8]);
    ot[j][sub * 8 + r8] = cv.s;
  }

  if (rc == 0 && t < 64) {
    float acc = 0.f;
    #pragma unroll
    for (int d = 0; d < 64; ++d)
      acc += toF(bsrc[h * 64 + d]) * bits2f((unsigned short)w[d][t]);
    outb[h * 64 + t + noff] = __float2bfloat16(acc);
  }
  __syncthreads();
  {
    const int nn = t >> 2;
    const int kx = (t & 3) * 8;
    short8 v;
    #pragma unroll
    for (int x = 0; x < 8; ++x) v[x] = ot[nn][kx + x];
    *(short8*)&outT[(size_t)(h * 64 + nn + noff) * 256 + rc * 32 + kx] = v;
  }
}

// -------------------------------------------------------------------------
// Multi-output MFMA GEMM. Tile 128(M) x 128(N), BK=64, 4 waves in 2x2.
// XCD-aware swizzle: blocks sharing an A-tile are 8 apart in dispatch order
// so round-robin XCD assignment puts them on ONE XCD -> A re-reads hit L2.
// [measured r10: non-LN pipeline dropped ~100 us vs r9 with this swizzle]
// -------------------------------------------------------------------------
__global__ __launch_bounds__(256, 4) void mfma_gemm128(
    const void* __restrict__ A, const unsigned* __restrict__ aflag,
    MultiDesc md, int M, int ntiles, int nslab)
{
  __shared__ short As[128][72];
  __shared__ short Bs[128][72];
  const int lid = blockIdx.x;
  const int grp = lid / (8 * nslab);
  const int rem = lid - grp * 8 * nslab;
  const int slab = rem >> 3;
  const int tx = grp * 8 + (rem & 7);
  if (tx >= ntiles) return;
  const GemmDesc d = md.d[slab];
  const bool abf = (*aflag != 0u);
  const int t = threadIdx.x;
  const int bm = tx * 128;
  const int lane = t & 63;
  const int wid  = t >> 6;
  const int wm = (wid >> 1) * 64;
  const int wn = (wid & 1) * 64;
  const int col16 = lane & 15;
  const int quad  = lane >> 4;
  const int rr = t >> 3;
  const int kk = (t & 7) * 8;

  float4v acc[4][4];
  #pragma unroll
  for (int mi = 0; mi < 4; ++mi)
    #pragma unroll
    for (int ni = 0; ni < 4; ++ni) acc[mi][ni] = (float4v){0.f, 0.f, 0.f, 0.f};

  for (int k0 = 0; k0 < 256; k0 += 64) {
    #pragma unroll
    for (int it = 0; it < 4; ++it) {
      const int row = it * 32 + rr;
      const int grow = bm + row;
      short8 v = (short8){0, 0, 0, 0, 0, 0, 0, 0};
      if (grow < M) {
        if (abf) {
          v = *(const short8*)((const short*)A + (size_t)grow * 256 + k0 + kk);
        } else {
          const float* ap = (const float*)A + (size_t)grow * 256 + k0 + kk;
          #pragma unroll
          for (int j = 0; j < 8; ++j) {
            union { bf16 h; short s; } cv;
            cv.h = __float2bfloat16(ap[j]);
            v[j] = cv.s;
          }
        }
      }
      *(short8*)&As[row][kk] = v;
    }
    #pragma unroll
    for (int it = 0; it < 4; ++it) {
      const int n = it * 32 + rr;
      *(short8*)&Bs[n][kk] = *(const short8*)&d.wt[(size_t)n * 256 + k0 + kk];
    }
    __syncthreads();

    #pragma unroll
    for (int ks = 0; ks < 64; ks += 32) {
      short8 bfr[4];
      #pragma unroll
      for (int ni = 0; ni < 4; ++ni)
        bfr[ni] = *(const short8*)&Bs[wn + ni * 16 + col16][ks + quad * 8];
      #pragma unroll
      for (int mi = 0; mi < 4; ++mi) {
        const short8 afr = *(const short8*)&As[wm + mi * 16 + col16][ks + quad * 8];
        #pragma unroll
        for (int ni = 0; ni < 4; ++ni)
          acc[mi][ni] = __builtin_amdgcn_mfma_f32_16x16x32_bf16(afr, bfr[ni], acc[mi][ni], 0, 0, 0);
      }
    }
    __syncthreads();
  }

  #pragma unroll
  for (int ni = 0; ni < 4; ++ni) {
    const int col = wn + ni * 16 + col16;
    const float bc = toF(d.bias[col]);
    const int gcol = d.coff + col;
    #pragma unroll
    for (int mi = 0; mi < 4; ++mi) {
      #pragma unroll
      for (int r = 0; r < 4; ++r) {
        const int row = bm + wm + mi * 16 + quad * 4 + r;
        if (row < M) {
          float v = acc[mi][ni][r] + bc;
          if (d.act == 1) v = gelu_exact(v);
          const size_t idx = (size_t)row * d.ldc + gcol;
          if (d.otype == 0) ((bf16*)d.c)[idx] = __float2bfloat16(v);
          else              ((float*)d.c)[idx] = v;
        }
      }
    }
  }
}

// -------------------------------------------------------------------------
// CSR gather v2: one wave per dst node, split into two 32-lane halves over
// alternate edges; 16B loads; 3-round 8-lane head reduction.
// -------------------------------------------------------------------------
__global__ __launch_bounds__(256) void gather_kernel(
    const bf16* __restrict__ q, const bf16* __restrict__ km,
    const int* __restrict__ srcs, const bf16* __restrict__ ews,
    const int* __restrict__ offs, const bf16* __restrict__ pri,
    bf16* __restrict__ agg, int Nd, int addPrev, float finalScale)
{
  const int lane = threadIdx.x & 63;
  const int wid  = threadIdx.x >> 6;
  const int node = blockIdx.x * 4 + wid;
  if (node >= Nd) return;
  const int h  = lane >> 5;
  const int sl = lane & 31;
  const float prih = toF(pri[sl >> 3]);

  union B8 { uint4 u; unsigned short s[8]; };
  B8 qv;
  qv.u = ((const uint4*)(q + (size_t)node * 256))[sl];
  float qf[8];
  #pragma unroll
  for (int j = 0; j < 8; ++j) qf[j] = bits2f(qv.s[j]);

  float acc[8] = {};
  const int beg = offs[node], end = offs[node + 1];
  for (int idx = beg + h; idx < end; idx += 2) {
    const int s = srcs[idx];
    const float w = toF(ews[idx]);
    B8 kb;
    kb.u = ((const uint4*)(km + (size_t)s * 512))[sl];
    float dot = 0.f;
    #pragma unroll
    for (int j = 0; j < 8; ++j) dot += qf[j] * bits2f(kb.s[j]);
    dot += __shfl_xor(dot, 1);
    dot += __shfl_xor(dot, 2);
    dot += __shfl_xor(dot, 4);
    const float a = w * sigmoidf_(dot * prih * 0.125f);
    B8 mb;
    mb.u = ((const uint4*)(km + (size_t)s * 512 + 256))[sl];
    #pragma unroll
    for (int j = 0; j < 8; ++j) acc[j] += bits2f(mb.s[j]) * a;
  }

  #pragma unroll
  for (int j = 0; j < 8; ++j) acc[j] += __shfl_xor(acc[j], 32);

  if (h == 0) {
    bf16* out = agg + (size_t)node * 256 + sl * 8;
    if (addPrev) {
      B8 pb;
      pb.u = *(const uint4*)out;
      #pragma unroll
      for (int j = 0; j < 8; ++j) acc[j] += bits2f(pb.s[j]);
    }
    B8 ov;
    #pragma unroll
    for (int j = 0; j < 8; ++j) {
      union { bf16 h; unsigned short u; } cv;
      cv.h = __float2bfloat16(acc[j] * finalScale);
      ov.s[j] = cv.u;
    }
    *(uint4*)out = ov.u;
  }
}

// -------------------------------------------------------------------------
// o = tr*alpha + feat*(1-alpha); feat = bf16(LN(o)*g + b). One wave per node.
// -------------------------------------------------------------------------
__global__ __launch_bounds__(256) void skip_ln(
    const float* __restrict__ tr, bf16* __restrict__ feat,
    const bf16* __restrict__ skipv, const bf16* __restrict__ g,
    const bf16* __restrict__ b, int N)
{
  const int lane = threadIdx.x & 63;
  const int wid  = threadIdx.x >> 6;
  const int node = blockIdx.x * 4 + wid;
  if (node >= N) return;
  const float alpha = sigmoidf_(toF(*skipv));
  const float4 t = ((const float4*)(tr + (size_t)node * 256))[lane];
  union B4 { uint2 u; unsigned short s[4]; };
  B4 fb;
  fb.u = ((const uint2*)(feat + (size_t)node * 256))[lane];
  float o[4];
  o[0] = t.x * alpha + bits2f(fb.s[0]) * (1.f - alpha);
  o[1] = t.y * alpha + bits2f(fb.s[1]) * (1.f - alpha);
  o[2] = t.z * alpha + bits2f(fb.s[2]) * (1.f - alpha);
  o[3] = t.w * alpha + bits2f(fb.s[3]) * (1.f - alpha);

  float sum = o[0] + o[1] + o[2] + o[3];
  #pragma unroll
  for (int off = 32; off; off >>= 1) sum += __shfl_xor(sum, off);
  const float mu = sum * (1.f / 256.f);

  float dd[4], sq = 0.f;
  #pragma unroll
  for (int j = 0; j < 4; ++j) { dd[j] = o[j] - mu; sq += dd[j] * dd[j]; }
  #pragma unroll
  for (int off = 32; off; off >>= 1) sq += __shfl_xor(sq, off);
  const float rs = rsqrtf(sq * (1.f / 256.f) + 1e-5f);

  bf16* fout = feat + (size_t)node * 256 + lane * 4;
  #pragma unroll
  for (int j = 0; j < 4; ++j) {
    float r = dd[j] * rs * toF(g[lane * 4 + j]) + toF(b[lane * 4 + j]);
    fout[j] = __float2bfloat16(r);
  }
}

// -------------------------------------------------------------------------
// out[M,64] = A[M,256] @ W[256,64] + b[64]; output dtype per *flag.
// -------------------------------------------------------------------------
__global__ __launch_bounds__(256) void out_gemm(
    const bf16* __restrict__ A, const bf16* __restrict__ W,
    const bf16* __restrict__ bias, void* __restrict__ out,
    const unsigned* __restrict__ flag, int M)
{
  __shared__ float Ws[64][64];
  const bool obf = (*flag != 0u);
  const int tid = threadIdx.x;
  const int row = blockIdx.x * 64 + (tid >> 2);
  const int c0 = (tid & 3) * 16;
  const int arow = (row < M) ? row : 0;
  const bf16* a = A + (size_t)arow * 256;
  float acc[16] = {};
  for (int k0 = 0; k0 < 256; k0 += 64) {
    for (int i = tid; i < 4096; i += 256)
      Ws[i >> 6][i & 63] = toF(W[(size_t)(k0 + (i >> 6)) * 64 + (i & 63)]);
    __syncthreads();
    for (int k = 0; k < 64; ++k) {
      const float av = toF(a[k0 + k]);
      #pragma unroll
      for (int j = 0; j < 16; ++j) acc[j] += av * Ws[k][c0 + j];
    }
    __syncthreads();
  }
  if (row < M) {
    #pragma unroll
    for (int j = 0; j < 16; ++j) {
      const float v = acc[j] + toF(bias[c0 + j]);
      const size_t idx = (size_t)row * 64 + c0 + j;
      if (obf) ((bf16*)out)[idx] = __float2bfloat16(v);
      else     ((float*)out)[idx] = v;
    }
  }
}

// -------------------------------------------------------------------------
extern "C" void kernel_launch(void* const* d_in, const int* in_sizes, int n_in,
                              void* d_out, int out_size, void* d_ws, size_t ws_size,
                              hipStream_t stream) {
  const int* src_wb  = (const int*)d_in[23];
  const int* dst_wb  = (const int*)d_in[24];
  const int* src_w   = (const int*)d_in[25];
  const int* dst_w   = (const int*)d_in[26];
  const int* src_c   = (const int*)d_in[27];
  const int* dst_c   = (const int*)d_in[28];

  // ---- workspace carve (~166 MB total) ----
  char* base = (char*)d_ws;
  unsigned* flags = (unsigned*)base;                       // 256 B
  bf16* canon = (bf16*)(base + 256);
  char* p = base + 256 + (((size_t)kCanonTotal * 2 + 511) & ~(size_t)511);
  bf16* adWT = (bf16*)p;                     // 2 x 65536
  bf16* qWT  = adWT + (size_t)2 * 65536;     // 4 x 65536
  bf16* aWT  = qWT  + (size_t)4 * 65536;     // 4 x 65536
  bf16* KMeffT = aWT + (size_t)4 * 65536;    // 6 x 512*256
  bf16* kmbeT  = KMeffT + (size_t)6 * 512 * 256;  // 6 x 512
  char* pc = (char*)(((size_t)(kmbeT + 6 * 512) + 511) & ~(size_t)511);
  // CSR region
  int* cur_wb  = (int*)pc;
  int* cur_w   = cur_wb + (kNA + 1);
  int* cur_c   = cur_w + (kNP + 1);
  int* offs_wb = cur_c + (kNP + 1);
  int* offs_w  = offs_wb + (kNA + 1);
  int* offs_c  = offs_w + (kNP + 1);
  int* srcs_wb = offs_c + (kNP + 1);
  int* srcs_w  = srcs_wb + kEWB;
  int* srcs_c  = srcs_w + kEW;
  bf16* ews_wb = (bf16*)(srcs_c + kEC);
  bf16* ews_w  = ews_wb + kEWB;
  bf16* ews_c  = ews_w + kEW;
  int* bsums   = (int*)(ews_c + kEC);     // [3][32]
  int* totals  = bsums + 96;              // [3]
  char* p2 = (char*)(((size_t)(totals + 3) + 511) & ~(size_t)511);
  bf16* fa  = (bf16*)p2;                  // [NA,256]
  bf16* fp_ = fa + (size_t)kNA * 256;     // [NP,256]
  char* R   = (char*)(fp_ + (size_t)kNP * 256);
  bf16* qa   = (bf16*)R;                  // [NA,256]
  bf16* qp   = qa + (size_t)kNA * 256;    // [NP,256]
  bf16* km_a = qp + (size_t)kNP * 256;    // [NA,512]
  bf16* km_p = km_a + (size_t)kNA * 512;  // [NP,512]
  float* tr_a = (float*)R;                // fp32 view of R, disjoint lifetime
  float* tr_p = tr_a + (size_t)kNA * 256;
  char* afterR = R + ((size_t)(kNA + kNP) * 256 + (size_t)(kNA + kNP) * 512) * sizeof(bf16);
  bf16* agg_a = (bf16*)afterR;            // [NA,256]
  bf16* agg_p = agg_a + (size_t)kNA * 256;// [NP,256]

  const bf16* c_ew_wb = canon + kOff(0);
  const bf16* c_ew_w  = canon + kOff(1);
  const bf16* c_ew_c  = canon + kOff(2);
  const bf16* c_adW   = canon + kOff(3);
  const bf16* c_adb   = canon + kOff(4);
  const bf16* c_kW    = canon + kOff(5);
  const bf16* c_kb    = canon + kOff(6);
  const bf16* c_qW    = canon + kOff(7);
  const bf16* c_qb    = canon + kOff(8);
  const bf16* c_mW    = canon + kOff(9);
  const bf16* c_mb    = canon + kOff(10);
  const bf16* c_aW    = canon + kOff(11);
  const bf16* c_ab    = canon + kOff(12);
  const bf16* c_wpri  = canon + kOff(13);
  const bf16* c_watt  = canon + kOff(14);
  const bf16* c_wmsg  = canon + kOff(15);
  const bf16* c_skip  = canon + kOff(16);
  const bf16* c_lng   = canon + kOff(17);
  const bf16* c_lnb   = canon + kOff(18);
  const bf16* c_outW  = canon + kOff(19);
  const bf16* c_outb  = canon + kOff(20);

  const unsigned* fIn = flags + 0;
  const unsigned* f1  = flags + 1;

  detect_dtype<<<1, 256, 0, stream>>>((const unsigned*)d_in[0], flags);

  CanonArgs ca;
  for (int s = 0; s < kNSeg; ++s) { ca.n[s] = kSegN[s]; ca.dstOff[s] = (unsigned)kOff(s); }
  const int srcIdx[kNSeg] = {2,3,4, 5,6, 7,8, 9,10, 11,12, 13,14, 15, 16,17, 18,19,20, 21,22};
  for (int s = 0; s < kNSeg; ++s) ca.src[s] = d_in[srcIdx[s]];
  canon_kernel<<<dim3(1172, kNSeg), 256, 0, stream>>>(ca, canon, flags);

  // ---- transpose the 10 dense 256x256 weights into [n][k] layout ----
  TransArgs ta;
  ta.src[0] = c_adW;              ta.dst[0] = adWT;
  ta.src[1] = c_adW + 65536;      ta.dst[1] = adWT + 65536;
  for (int m = 0; m < 4; ++m) { ta.src[2 + m] = c_qW + (size_t)m * 65536; ta.dst[2 + m] = qWT + (size_t)m * 65536; }
  for (int m = 0; m < 4; ++m) { ta.src[6 + m] = c_aW + (size_t)m * 65536; ta.dst[6 + m] = aWT + (size_t)m * 65536; }
  transpose_w<<<dim3(4, 4, 10), 256, 0, stream>>>(ta);

  // ---- CSR build ----
  hipMemsetAsync(cur_wb, 0, (size_t)((kNA + 1) + 2 * (kNP + 1)) * 4, stream);
  csr_hist<<<(kEWB + 255) / 256, 256, 0, stream>>>(dst_wb, kEWB, cur_wb);
  csr_hist<<<(kEW  + 255) / 256, 256, 0, stream>>>(dst_w,  kEW,  cur_w);
  csr_hist<<<(kEC  + 255) / 256, 256, 0, stream>>>(dst_c,  kEC,  cur_c);
  ScanArgs sa;
  sa.deg[0] = cur_wb;  sa.offs[0] = offs_wb; sa.N[0] = kNA;
  sa.deg[1] = cur_w;   sa.offs[1] = offs_w;  sa.N[1] = kNP;
  sa.deg[2] = cur_c;   sa.offs[2] = offs_c;  sa.N[2] = kNP;
  sa.bsums = bsums;
  scan_l1<<<dim3(32, 3), 256, 0, stream>>>(sa);
  scan_l2<<<3, 64, 0, stream>>>(bsums, totals);
  scan_l3<<<dim3(20, 3), 256, 0, stream>>>(sa, totals);
  csr_scatter<<<(kEWB + 255) / 256, 256, 0, stream>>>(dst_wb, src_wb, c_ew_wb, kEWB, cur_wb, srcs_wb, ews_wb);
  csr_scatter<<<(kEW  + 255) / 256, 256, 0, stream>>>(dst_w,  src_w,  c_ew_w,  kEW,  cur_w,  srcs_w,  ews_w);
  csr_scatter<<<(kEC  + 255) / 256, 256, 0, stream>>>(dst_c,  src_c,  c_ew_c,  kEC,  cur_c,  srcs_c,  ews_c);

  // fused K|M effective weights (K: noff=0, M: noff=256)
  combine_weights<<<dim3(8, 24), 256, 0, stream>>>(c_kW, c_kb, c_watt, KMeffT, kmbeT, 0);
  combine_weights<<<dim3(8, 24), 256, 0, stream>>>(c_mW, c_mb, c_wmsg, KMeffT, kmbeT, 256);

  auto sgrid = [](int m, int nslab) {
    const int nt = (m + 127) / 128;
    return dim3((unsigned)(((nt + 7) / 8) * 8 * nslab));
  };
  auto ntl = [](int m) { return (m + 127) / 128; };
  auto mkd = [](const bf16* wt, const bf16* bias, void* c, int ldc, int coff,
                int act, int otype) {
    GemmDesc g;
    g.wt = (const short*)wt; g.bias = bias; g.c = c; g.ldc = ldc;
    g.coff = coff; g.act = act; g.otype = otype; g.pad = 0;
    return g;
  };

  // adapt: feats = gelu(x @ adapt_W + adapt_b)
  {
    MultiDesc md{};
    md.d[0] = mkd(adWT,                c_adb,        fa, 256, 0,   1, 0);
    md.d[1] = mkd(adWT + 128 * 256,    c_adb + 128,  fa, 256, 128, 1, 0);
    mfma_gemm128<<<sgrid(kNA, 2), 256, 0, stream>>>(d_in[0], fIn, md, kNA, ntl(kNA), 2);
    md.d[0] = mkd(adWT + 65536,        c_adb + 256,  fp_, 256, 0,   1, 0);
    md.d[1] = mkd(adWT + 65536 + 128 * 256, c_adb + 384, fp_, 256, 128, 1, 0);
    mfma_gemm128<<<sgrid(kNP, 2), 256, 0, stream>>>(d_in[1], fIn, md, kNP, ntl(kNP), 2);
  }

  for (int l = 0; l < 2; ++l) {
    const bf16* qW_a = qWT + (size_t)(l * 2 + 0) * 65536;
    const bf16* qW_p = qWT + (size_t)(l * 2 + 1) * 65536;
    const bf16* qb_a = c_qb + (l * 2 + 0) * 256;
    const bf16* qb_p = c_qb + (l * 2 + 1) * 256;
    const bf16* KM_c  = KMeffT + (size_t)(l * 3 + 0) * 512 * 256;
    const bf16* KM_w  = KMeffT + (size_t)(l * 3 + 1) * 512 * 256;
    const bf16* KM_wb = KMeffT + (size_t)(l * 3 + 2) * 512 * 256;
    const bf16* kb_c  = kmbeT + (l * 3 + 0) * 512;
    const bf16* kb_w  = kmbeT + (l * 3 + 1) * 512;
    const bf16* kb_wb = kmbeT + (l * 3 + 2) * 512;

    // authors-proj: Q_a (2 slabs) + KM_w (4 slabs) from fa
    {
      MultiDesc md{};
      md.d[0] = mkd(qW_a,             qb_a,        qa,   256, 0,   0, 0);
      md.d[1] = mkd(qW_a + 128 * 256, qb_a + 128,  qa,   256, 128, 0, 0);
      for (int s = 0; s < 4; ++s)
        md.d[2 + s] = mkd(KM_w + (size_t)s * 128 * 256, kb_w + s * 128, km_a, 512, s * 128, 0, 0);
      mfma_gemm128<<<sgrid(kNA, 6), 256, 0, stream>>>(fa, f1, md, kNA, ntl(kNA), 6);
    }
    // papers-proj: Q_p (2 slabs) + KM_wb (4 slabs) from fp_
    {
      MultiDesc md{};
      md.d[0] = mkd(qW_p,             qb_p,        qp,   256, 0,   0, 0);
      md.d[1] = mkd(qW_p + 128 * 256, qb_p + 128,  qp,   256, 128, 0, 0);
      for (int s = 0; s < 4; ++s)
        md.d[2 + s] = mkd(KM_wb + (size_t)s * 128 * 256, kb_wb + s * 128, km_p, 512, s * 128, 0, 0);
      mfma_gemm128<<<sgrid(kNP, 6), 256, 0, stream>>>(fp_, f1, md, kNP, ntl(kNP), 6);
    }

    // WRITTEN_BY: paper -> author
    gather_kernel<<<(kNA + 3) / 4, 256, 0, stream>>>(
        qa, km_p, srcs_wb, ews_wb, offs_wb, c_wpri + (l * 3 + 2) * 4,
        agg_a, kNA, 0, 1.f);
    // WRITES: author -> paper
    gather_kernel<<<(kNP + 3) / 4, 256, 0, stream>>>(
        qp, km_a, srcs_w, ews_w, offs_w, c_wpri + (l * 3 + 1) * 4,
        agg_p, kNP, 0, 1.f);

    // cites-KM: reuse km_p (wb gather already done in stream order)
    {
      MultiDesc md{};
      for (int s = 0; s < 4; ++s)
        md.d[s] = mkd(KM_c + (size_t)s * 128 * 256, kb_c + s * 128, km_p, 512, s * 128, 0, 0);
      mfma_gemm128<<<sgrid(kNP, 4), 256, 0, stream>>>(fp_, f1, md, kNP, ntl(kNP), 4);
    }
    // CITES: paper -> paper, chained add + 0.5 mean
    gather_kernel<<<(kNP + 3) / 4, 256, 0, stream>>>(
        qp, km_p, srcs_c, ews_c, offs_c, c_wpri + (l * 3 + 0) * 4,
        agg_p, kNP, 1, 0.5f);

    // A-projection of aggregates -> fp32 tr (aliases R; gathers are done)
    {
      const bf16* aW_a = aWT + (size_t)(l * 2 + 0) * 65536;
      const bf16* aW_p = aWT + (size_t)(l * 2 + 1) * 65536;
      MultiDesc md{};
      md.d[0] = mkd(aW_a,             c_ab + (l * 2 + 0) * 256,       tr_a, 256, 0,   0, 1);
      md.d[1] = mkd(aW_a + 128 * 256, c_ab + (l * 2 + 0) * 256 + 128, tr_a, 256, 128, 0, 1);
      mfma_gemm128<<<sgrid(kNA, 2), 256, 0, stream>>>(agg_a, f1, md, kNA, ntl(kNA), 2);
      md.d[0] = mkd(aW_p,             c_ab + (l * 2 + 1) * 256,       tr_p, 256, 0,   0, 1);
      md.d[1] = mkd(aW_p + 128 * 256, c_ab + (l * 2 + 1) * 256 + 128, tr_p, 256, 128, 0, 1);
      mfma_gemm128<<<sgrid(kNP, 2), 256, 0, stream>>>(agg_p, f1, md, kNP, ntl(kNP), 2);
    }

    skip_ln<<<kNA / 4, 256, 0, stream>>>(
        tr_a, fa,  c_skip + l * 3 + 0, c_lng + (l * 2 + 0) * 256, c_lnb + (l * 2 + 0) * 256, kNA);
    skip_ln<<<kNP / 4, 256, 0, stream>>>(
        tr_p, fp_, c_skip + l * 3 + 1, c_lng + (l * 2 + 1) * 256, c_lnb + (l * 2 + 1) * 256, kNP);
  }

  out_gemm<<<kNP / 64, 256, 0, stream>>>(fp_, c_outW, c_outb, d_out, fIn, kNP);
}

// Round 12
// 853.905 us; speedup vs baseline: 1.2195x; 1.0596x over previous
//
#include <hip/hip_runtime.h>
#include <hip/hip_bf16.h>
#include <math.h>

using bf16 = __hip_bfloat16;

typedef __attribute__((ext_vector_type(8))) short short8;   // 8 bf16 (4 VGPRs)
typedef __attribute__((ext_vector_type(4))) float float4v;  // MFMA acc

static constexpr int kNA  = 20000;
static constexpr int kNP  = 40000;
static constexpr int kEWB = 150000;
static constexpr int kEW  = 150000;
static constexpr int kEC  = 300000;

// ---- canonical bf16 input region ----
static constexpr int kNSeg = 21;
static constexpr int kSegN[kNSeg] = {
  150000, 150000, 300000,           // ew_wb, ew_w, ew_c
  131072, 512,                      // adW, adb
  262144, 1024,                     // kW, kb
  262144, 1024,                     // qW, qb
  262144, 1024,                     // mW, mb
  262144, 1024,                     // aW, ab
  24,                               // wpri
  98304, 98304,                     // watt, wmsg
  6, 1024, 1024,                    // skip, lng, lnb
  16384, 64                         // outW, outb
};
static constexpr size_t kOff(int s) {
  size_t o = 0;
  for (int i = 0; i < s; ++i) o += (size_t)kSegN[i];
  return o;
}
static constexpr size_t kCanonTotal = kOff(kNSeg);

struct CanonArgs {
  const void* src[kNSeg];
  int n[kNSeg];
  unsigned dstOff[kNSeg];
};
struct TransArgs {
  const bf16* src[10];
  bf16* dst[10];
};
// per-slab GEMM descriptor (slab = 128 output cols); per-slab A/M/ntiles
struct GemmDesc {
  const short* wt;   // [128][256] n-major slab
  const bf16* bias;  // 128 entries (slab-local)
  const void* A;     // input activations
  void* c;           // output base
  int ldc;           // in elements
  int coff;          // global col offset of this slab in C
  int act;           // 1 = gelu
  int otype;         // 0 = bf16, 1 = fp32
  int M;             // rows of A
  int ntiles;        // ceil(M/128)
};
struct MultiDesc { GemmDesc d[10]; };
// three-relation scan / hist / scatter descriptors
struct ScanArgs {
  int* deg[3];
  int* offs[3];
  int* bsums;
  int N[3];
};
struct HistArgs {
  const int* dst[3];
  int* cnt[3];
  int E[3];
};
struct ScatArgs {
  const int* dst[3];
  const int* src[3];
  const bf16* ew[3];
  int* cur[3];
  int* srcs[3];
  bf16* ews[3];
  int E[3];
};
// gather descriptor
struct GatherDesc {
  const bf16* q;
  const bf16* km;
  const int* srcs;
  const bf16* ews;
  const int* offs;
  const bf16* pri;
  bf16* agg;
  int Nd;
  int addPrev;
  float scale;
};

__device__ __forceinline__ float toF(float x) { return x; }
__device__ __forceinline__ float toF(bf16 x)  { return __bfloat162float(x); }
__device__ __forceinline__ float bits2f(unsigned short b) {
  unsigned int u = ((unsigned int)b) << 16;
  return __uint_as_float(u);
}
__device__ __forceinline__ float sigmoidf_(float x) { return 1.0f / (1.0f + expf(-x)); }
__device__ __forceinline__ float gelu_exact(float x) {
  return 0.5f * x * (1.0f + erff(x * 0.70710678118654752f));
}

// -------------------------------------------------------------------------
// Input-dtype sniffer. flags: [0]=isBf16 [1]=1
// -------------------------------------------------------------------------
__global__ __launch_bounds__(256) void detect_dtype(
    const unsigned* __restrict__ x, unsigned* __restrict__ flags)
{
  __shared__ int cnt;
  if (threadIdx.x == 0) cnt = 0;
  __syncthreads();
  unsigned w = x[threadIdx.x];
  unsigned e = (w >> 7) & 0xFFu;
  if (e >= 110u && e <= 140u) atomicAdd(&cnt, 1);
  __syncthreads();
  if (threadIdx.x == 0) {
    flags[0] = (cnt >= 128) ? 1u : 0u;
    flags[1] = 1u;
  }
}

__global__ __launch_bounds__(256) void canon_kernel(
    CanonArgs a, bf16* __restrict__ dst, const unsigned* __restrict__ flags)
{
  const int s = blockIdx.y;
  const int i = blockIdx.x * 256 + threadIdx.x;
  if (i >= a.n[s]) return;
  bf16 v;
  if (flags[0]) v = ((const bf16*)a.src[s])[i];
  else          v = __float2bfloat16(((const float*)a.src[s])[i]);
  dst[a.dstOff[s] + i] = v;
}

// -------------------------------------------------------------------------
// Batched 256x256 weight transpose: dst[n][k] = src[k][n]. grid (4,4,10).
// -------------------------------------------------------------------------
__global__ __launch_bounds__(256) void transpose_w(TransArgs ta)
{
  const int m = blockIdx.z;
  const short* src = (const short*)ta.src[m];
  short* dst = (short*)ta.dst[m];
  const int k0 = blockIdx.x * 64, n0 = blockIdx.y * 64;
  __shared__ short tile[64][65];
  const int tx = threadIdx.x & 63, ty = threadIdx.x >> 6;
  for (int i = ty; i < 64; i += 4)
    tile[i][tx] = src[(size_t)(k0 + i) * 256 + n0 + tx];
  __syncthreads();
  for (int i = ty; i < 64; i += 4)
    dst[(size_t)(n0 + i) * 256 + k0 + tx] = tile[tx][i];
}

// -------------------------------------------------------------------------
// CSR build: fused histogram -> 3-level parallel scan -> fused scatter.
// -------------------------------------------------------------------------
__global__ __launch_bounds__(256) void csr_hist(HistArgs h)
{
  const int rel = blockIdx.y;
  const int i = blockIdx.x * 256 + threadIdx.x;
  if (i < h.E[rel]) atomicAdd(&h.cnt[rel][h.dst[rel][i]], 1);
}

__global__ __launch_bounds__(256) void scan_l1(ScanArgs a)
{
  const int rel = blockIdx.y;
  const int N = a.N[rel];
  const int t = threadIdx.x;
  const int lane = t & 63;
  const int wid = t >> 6;
  const int i0 = blockIdx.x * 2048 + t * 8;
  const int* deg = a.deg[rel];
  int v[8];
  int T = 0;
  #pragma unroll
  for (int j = 0; j < 8; ++j) {
    v[j] = (i0 + j < N) ? deg[i0 + j] : 0;
    T += v[j];
  }
  int incl = T;
  #pragma unroll
  for (int off = 1; off < 64; off <<= 1) {
    const int u = __shfl_up(incl, off);
    if (lane >= off) incl += u;
  }
  __shared__ int wsum[4];
  if (lane == 63) wsum[wid] = incl;
  __syncthreads();
  int woff = 0;
  #pragma unroll
  for (int wp = 0; wp < 4; ++wp) if (wp < wid) woff += wsum[wp];
  int run = woff + incl - T;
  int* offs = a.offs[rel];
  #pragma unroll
  for (int j = 0; j < 8; ++j) {
    if (i0 + j < N) offs[i0 + j] = run;
    run += v[j];
  }
  if (t == 0)
    a.bsums[rel * 32 + blockIdx.x] = wsum[0] + wsum[1] + wsum[2] + wsum[3];
}

__global__ __launch_bounds__(64) void scan_l2(int* __restrict__ bsums,
                                              int* __restrict__ totals)
{
  const int rel = blockIdx.x;
  const int lane = threadIdx.x;
  const int v = (lane < 32) ? bsums[rel * 32 + lane] : 0;
  int incl = v;
  #pragma unroll
  for (int off = 1; off < 64; off <<= 1) {
    const int u = __shfl_up(incl, off);
    if (lane >= off) incl += u;
  }
  if (lane < 32) bsums[rel * 32 + lane] = incl - v;
  if (lane == 63) totals[rel] = incl;
}

__global__ __launch_bounds__(256) void scan_l3(ScanArgs a,
                                               const int* __restrict__ totals)
{
  const int rel = blockIdx.y;
  const int N = a.N[rel];
  const int i0 = blockIdx.x * 2048 + threadIdx.x * 8;
  const int boff = a.bsums[rel * 32 + blockIdx.x];
  int* offs = a.offs[rel];
  int* cur = a.deg[rel];
  #pragma unroll
  for (int j = 0; j < 8; ++j) {
    const int idx = i0 + j;
    if (idx < N) {
      const int o = offs[idx] + boff;
      offs[idx] = o;
      cur[idx] = o;
    }
  }
  if (blockIdx.x == 0 && threadIdx.x == 0) offs[N] = totals[rel];
}

__global__ __launch_bounds__(256) void csr_scatter(ScatArgs s)
{
  const int rel = blockIdx.y;
  const int i = blockIdx.x * 256 + threadIdx.x;
  if (i >= s.E[rel]) return;
  const int p = atomicAdd(&s.cur[rel][s.dst[rel][i]], 1);
  s.srcs[rel][p] = s.src[rel][i];
  s.ews[rel][p]  = s.ew[rel][i];
}

// -------------------------------------------------------------------------
// Fold per-head w_att/w_msg into K/M projections; emit fused-transposed
// KMT[l,e][512][256] bf16 + bias kmb[l,e][512]. grid (8, 24).
// -------------------------------------------------------------------------
__global__ __launch_bounds__(256) void combine_weights(
    const bf16* __restrict__ Wbig, const bf16* __restrict__ bbig,
    const bf16* __restrict__ wsm, bf16* __restrict__ KMT,
    bf16* __restrict__ kmb, int noff)
{
  const int blk = blockIdx.y;
  const int rc  = blockIdx.x;
  const int h = blk & 3;
  const int le = blk >> 2;
  const int e = le % 3;
  const int l = le / 3;
  const int st = (e == 1) ? 0 : 1;

  const short* Wsrc = (const short*)(Wbig + (size_t)(l * 2 + st) * 65536);
  const bf16*  bsrc = bbig + (size_t)(l * 2 + st) * 256;
  const short* wm   = (const short*)(wsm + ((size_t)(l * 3 + e) * 4 + h) * 4096);
  short* outT = (short*)(KMT + (size_t)(l * 3 + e) * 512 * 256);
  bf16* outb  = kmb + (size_t)(l * 3 + e) * 512;

  __shared__ short w[64][72];
  __shared__ short As[32][72];
  __shared__ short ot[64][40];

  const int t = threadIdx.x;
  {
    const int base = t * 16;
    const int r0 = base >> 6, c0 = base & 63;
    *(short8*)&w[r0][c0]     = *(const short8*)&wm[base];
    *(short8*)&w[r0][c0 + 8] = *(const short8*)&wm[base + 8];
  }
  {
    const int row = t >> 3;
    const int kc = (t & 7) * 8;
    *(short8*)&As[row][kc] =
        *(const short8*)&Wsrc[(size_t)(rc * 32 + row) * 256 + h * 64 + kc];
  }
  __syncthreads();

  const int j   = t & 63;
  const int sub = t >> 6;
  float accv[8] = {};
  #pragma unroll
  for (int d = 0; d < 64; ++d) {
    const float wd = bits2f((unsigned short)w[d][j]);
    #pragma unroll
    for (int r8 = 0; r8 < 8; ++r8)
      accv[r8] += bits2f((unsigned short)As[sub * 8 + r8][d]) * wd;
  }
  #pragma unroll
  for (int r8 = 0; r8 < 8; ++r8) {
    union { bf16 h; short s; } cv;
    cv.h = __float2bfloat16(accv[r8]);
    ot[j][sub * 8 + r8] = cv.s;
  }

  if (rc == 0 && t < 64) {
    float acc = 0.f;
    #pragma unroll
    for (int d = 0; d < 64; ++d)
      acc += toF(bsrc[h * 64 + d]) * bits2f((unsigned short)w[d][t]);
    outb[h * 64 + t + noff] = __float2bfloat16(acc);
  }
  __syncthreads();
  {
    const int nn = t >> 2;
    const int kx = (t & 3) * 8;
    short8 v;
    #pragma unroll
    for (int x = 0; x < 8; ++x) v[x] = ot[nn][kx + x];
    *(short8*)&outT[(size_t)(h * 64 + nn + noff) * 256 + rc * 32 + kx] = v;
  }
}

// -------------------------------------------------------------------------
// Multi-output MFMA GEMM with per-slab A/M/ntiles. Tile 128x128, BK=64,
// 4 waves in 2x2. XCD swizzle: same-tile blocks 8 apart -> same XCD
// [measured r11: FETCH 63->21.7 MB on papers-proj].
// -------------------------------------------------------------------------
__global__ __launch_bounds__(256, 4) void mfma_gemm128(
    const unsigned* __restrict__ aflag, MultiDesc md, int nslab)
{
  __shared__ short As[128][72];
  __shared__ short Bs[128][72];
  const int lid = blockIdx.x;
  const int grp = lid / (8 * nslab);
  const int rem = lid - grp * 8 * nslab;
  const int slab = rem >> 3;
  const int tx = grp * 8 + (rem & 7);
  const GemmDesc d = md.d[slab];
  if (tx >= d.ntiles) return;
  const bool abf = (*aflag != 0u);
  const int M = d.M;
  const int t = threadIdx.x;
  const int bm = tx * 128;
  const int lane = t & 63;
  const int wid  = t >> 6;
  const int wm = (wid >> 1) * 64;
  const int wn = (wid & 1) * 64;
  const int col16 = lane & 15;
  const int quad  = lane >> 4;
  const int rr = t >> 3;
  const int kk = (t & 7) * 8;

  float4v acc[4][4];
  #pragma unroll
  for (int mi = 0; mi < 4; ++mi)
    #pragma unroll
    for (int ni = 0; ni < 4; ++ni) acc[mi][ni] = (float4v){0.f, 0.f, 0.f, 0.f};

  for (int k0 = 0; k0 < 256; k0 += 64) {
    #pragma unroll
    for (int it = 0; it < 4; ++it) {
      const int row = it * 32 + rr;
      const int grow = bm + row;
      short8 v = (short8){0, 0, 0, 0, 0, 0, 0, 0};
      if (grow < M) {
        if (abf) {
          v = *(const short8*)((const short*)d.A + (size_t)grow * 256 + k0 + kk);
        } else {
          const float* ap = (const float*)d.A + (size_t)grow * 256 + k0 + kk;
          #pragma unroll
          for (int j = 0; j < 8; ++j) {
            union { bf16 h; short s; } cv;
            cv.h = __float2bfloat16(ap[j]);
            v[j] = cv.s;
          }
        }
      }
      *(short8*)&As[row][kk] = v;
    }
    #pragma unroll
    for (int it = 0; it < 4; ++it) {
      const int n = it * 32 + rr;
      *(short8*)&Bs[n][kk] = *(const short8*)&d.wt[(size_t)n * 256 + k0 + kk];
    }
    __syncthreads();

    #pragma unroll
    for (int ks = 0; ks < 64; ks += 32) {
      short8 bfr[4];
      #pragma unroll
      for (int ni = 0; ni < 4; ++ni)
        bfr[ni] = *(const short8*)&Bs[wn + ni * 16 + col16][ks + quad * 8];
      #pragma unroll
      for (int mi = 0; mi < 4; ++mi) {
        const short8 afr = *(const short8*)&As[wm + mi * 16 + col16][ks + quad * 8];
        #pragma unroll
        for (int ni = 0; ni < 4; ++ni)
          acc[mi][ni] = __builtin_amdgcn_mfma_f32_16x16x32_bf16(afr, bfr[ni], acc[mi][ni], 0, 0, 0);
      }
    }
    __syncthreads();
  }

  #pragma unroll
  for (int ni = 0; ni < 4; ++ni) {
    const int col = wn + ni * 16 + col16;
    const float bc = toF(d.bias[col]);
    const int gcol = d.coff + col;
    #pragma unroll
    for (int mi = 0; mi < 4; ++mi) {
      #pragma unroll
      for (int r = 0; r < 4; ++r) {
        const int row = bm + wm + mi * 16 + quad * 4 + r;
        if (row < M) {
          float v = acc[mi][ni][r] + bc;
          if (d.act == 1) v = gelu_exact(v);
          const size_t idx = (size_t)row * d.ldc + gcol;
          if (d.otype == 0) ((bf16*)d.c)[idx] = __float2bfloat16(v);
          else              ((float*)d.c)[idx] = v;
        }
      }
    }
  }
}

// -------------------------------------------------------------------------
// Fused CSR gather: two descriptors, block-range decode. Split-wave halves,
// 16B loads, 3-round 8-lane head reduction. out = scale*acc (+ prev).
// -------------------------------------------------------------------------
__global__ __launch_bounds__(256) void gather_fused(
    GatherDesc da, GatherDesc db, int blocksA)
{
  const GatherDesc d = (blockIdx.x < (unsigned)blocksA) ? da : db;
  const int bidx = (blockIdx.x < (unsigned)blocksA) ? blockIdx.x
                                                    : blockIdx.x - blocksA;
  const int lane = threadIdx.x & 63;
  const int wid  = threadIdx.x >> 6;
  const int node = bidx * 4 + wid;
  if (node >= d.Nd) return;
  const int h  = lane >> 5;
  const int sl = lane & 31;
  const float prih = toF(d.pri[sl >> 3]);

  union B8 { uint4 u; unsigned short s[8]; };
  B8 qv;
  qv.u = ((const uint4*)(d.q + (size_t)node * 256))[sl];
  float qf[8];
  #pragma unroll
  for (int j = 0; j < 8; ++j) qf[j] = bits2f(qv.s[j]);

  float acc[8] = {};
  const int beg = d.offs[node], end = d.offs[node + 1];
  for (int idx = beg + h; idx < end; idx += 2) {
    const int s = d.srcs[idx];
    const float w = toF(d.ews[idx]);
    B8 kb;
    kb.u = ((const uint4*)(d.km + (size_t)s * 512))[sl];
    float dot = 0.f;
    #pragma unroll
    for (int j = 0; j < 8; ++j) dot += qf[j] * bits2f(kb.s[j]);
    dot += __shfl_xor(dot, 1);
    dot += __shfl_xor(dot, 2);
    dot += __shfl_xor(dot, 4);
    const float a = w * sigmoidf_(dot * prih * 0.125f);
    B8 mb;
    mb.u = ((const uint4*)(d.km + (size_t)s * 512 + 256))[sl];
    #pragma unroll
    for (int j = 0; j < 8; ++j) acc[j] += bits2f(mb.s[j]) * a;
  }

  #pragma unroll
  for (int j = 0; j < 8; ++j) acc[j] += __shfl_xor(acc[j], 32);

  if (h == 0) {
    bf16* out = d.agg + (size_t)node * 256 + sl * 8;
    #pragma unroll
    for (int j = 0; j < 8; ++j) acc[j] *= d.scale;
    if (d.addPrev) {
      B8 pb;
      pb.u = *(const uint4*)out;
      #pragma unroll
      for (int j = 0; j < 8; ++j) acc[j] += bits2f(pb.s[j]);
    }
    B8 ov;
    #pragma unroll
    for (int j = 0; j < 8; ++j) {
      union { bf16 h; unsigned short u; } cv;
      cv.h = __float2bfloat16(acc[j]);
      ov.s[j] = cv.u;
    }
    *(uint4*)out = ov.u;
  }
}

// -------------------------------------------------------------------------
// Fused skip+LN over both node types: node-range decode. One wave per node.
// -------------------------------------------------------------------------
__global__ __launch_bounds__(256) void skip_ln2(
    const float* __restrict__ trA, bf16* __restrict__ featA,
    const bf16* __restrict__ skA, const bf16* __restrict__ gA_, const bf16* __restrict__ bA,
    const float* __restrict__ trP, bf16* __restrict__ featP,
    const bf16* __restrict__ skP, const bf16* __restrict__ gP, const bf16* __restrict__ bP,
    int NA, int Ntot)
{
  const int lane = threadIdx.x & 63;
  const int wid  = threadIdx.x >> 6;
  int node = blockIdx.x * 4 + wid;
  if (node >= Ntot) return;
  const float* tr; bf16* feat; const bf16 *sk, *g, *b;
  if (node < NA) { tr = trA; feat = featA; sk = skA; g = gA_; b = bA; }
  else { node -= NA; tr = trP; feat = featP; sk = skP; g = gP; b = bP; }

  const float alpha = sigmoidf_(toF(*sk));
  const float4 t = ((const float4*)(tr + (size_t)node * 256))[lane];
  union B4 { uint2 u; unsigned short s[4]; };
  B4 fb;
  fb.u = ((const uint2*)(feat + (size_t)node * 256))[lane];
  float o[4];
  o[0] = t.x * alpha + bits2f(fb.s[0]) * (1.f - alpha);
  o[1] = t.y * alpha + bits2f(fb.s[1]) * (1.f - alpha);
  o[2] = t.z * alpha + bits2f(fb.s[2]) * (1.f - alpha);
  o[3] = t.w * alpha + bits2f(fb.s[3]) * (1.f - alpha);

  float sum = o[0] + o[1] + o[2] + o[3];
  #pragma unroll
  for (int off = 32; off; off >>= 1) sum += __shfl_xor(sum, off);
  const float mu = sum * (1.f / 256.f);

  float dd[4], sq = 0.f;
  #pragma unroll
  for (int j = 0; j < 4; ++j) { dd[j] = o[j] - mu; sq += dd[j] * dd[j]; }
  #pragma unroll
  for (int off = 32; off; off >>= 1) sq += __shfl_xor(sq, off);
  const float rs = rsqrtf(sq * (1.f / 256.f) + 1e-5f);

  bf16* fout = feat + (size_t)node * 256 + lane * 4;
  #pragma unroll
  for (int j = 0; j < 4; ++j) {
    float r = dd[j] * rs * toF(g[lane * 4 + j]) + toF(b[lane * 4 + j]);
    fout[j] = __float2bfloat16(r);
  }
}

// -------------------------------------------------------------------------
// out[M,64] = A[M,256] @ W[256,64] + b[64]; output dtype per *flag.
// -------------------------------------------------------------------------
__global__ __launch_bounds__(256) void out_gemm(
    const bf16* __restrict__ A, const bf16* __restrict__ W,
    const bf16* __restrict__ bias, void* __restrict__ out,
    const unsigned* __restrict__ flag, int M)
{
  __shared__ float Ws[64][64];
  const bool obf = (*flag != 0u);
  const int tid = threadIdx.x;
  const int row = blockIdx.x * 64 + (tid >> 2);
  const int c0 = (tid & 3) * 16;
  const int arow = (row < M) ? row : 0;
  const bf16* a = A + (size_t)arow * 256;
  float acc[16] = {};
  for (int k0 = 0; k0 < 256; k0 += 64) {
    for (int i = tid; i < 4096; i += 256)
      Ws[i >> 6][i & 63] = toF(W[(size_t)(k0 + (i >> 6)) * 64 + (i & 63)]);
    __syncthreads();
    for (int k = 0; k < 64; ++k) {
      const float av = toF(a[k0 + k]);
      #pragma unroll
      for (int j = 0; j < 16; ++j) acc[j] += av * Ws[k][c0 + j];
    }
    __syncthreads();
  }
  if (row < M) {
    #pragma unroll
    for (int j = 0; j < 16; ++j) {
      const float v = acc[j] + toF(bias[c0 + j]);
      const size_t idx = (size_t)row * 64 + c0 + j;
      if (obf) ((bf16*)out)[idx] = __float2bfloat16(v);
      else     ((float*)out)[idx] = v;
    }
  }
}

// -------------------------------------------------------------------------
extern "C" void kernel_launch(void* const* d_in, const int* in_sizes, int n_in,
                              void* d_out, int out_size, void* d_ws, size_t ws_size,
                              hipStream_t stream) {
  const int* src_wb  = (const int*)d_in[23];
  const int* dst_wb  = (const int*)d_in[24];
  const int* src_w   = (const int*)d_in[25];
  const int* dst_w   = (const int*)d_in[26];
  const int* src_c   = (const int*)d_in[27];
  const int* dst_c   = (const int*)d_in[28];

  // ---- workspace carve (~160 MB total) ----
  char* base = (char*)d_ws;
  unsigned* flags = (unsigned*)base;
  bf16* canon = (bf16*)(base + 256);
  char* p = base + 256 + (((size_t)kCanonTotal * 2 + 511) & ~(size_t)511);
  bf16* adWT = (bf16*)p;
  bf16* qWT  = adWT + (size_t)2 * 65536;
  bf16* aWT  = qWT  + (size_t)4 * 65536;
  bf16* KMeffT = aWT + (size_t)4 * 65536;    // 6 x 512*256
  bf16* kmbeT  = KMeffT + (size_t)6 * 512 * 256;
  char* pc = (char*)(((size_t)(kmbeT + 6 * 512) + 511) & ~(size_t)511);
  int* cur_wb  = (int*)pc;
  int* cur_w   = cur_wb + (kNA + 1);
  int* cur_c   = cur_w + (kNP + 1);
  int* offs_wb = cur_c + (kNP + 1);
  int* offs_w  = offs_wb + (kNA + 1);
  int* offs_c  = offs_w + (kNP + 1);
  int* srcs_wb = offs_c + (kNP + 1);
  int* srcs_w  = srcs_wb + kEWB;
  int* srcs_c  = srcs_w + kEW;
  bf16* ews_wb = (bf16*)(srcs_c + kEC);
  bf16* ews_w  = ews_wb + kEWB;
  bf16* ews_c  = ews_w + kEW;
  int* bsums   = (int*)(ews_c + kEC);
  int* totals  = bsums + 96;
  char* p2 = (char*)(((size_t)(totals + 3) + 511) & ~(size_t)511);
  bf16* fa  = (bf16*)p2;
  bf16* fp_ = fa + (size_t)kNA * 256;
  char* R   = (char*)(fp_ + (size_t)kNP * 256);
  bf16* qa   = (bf16*)R;                  // [NA,256]
  bf16* qp   = qa + (size_t)kNA * 256;    // [NP,256]
  bf16* km_a = qp + (size_t)kNP * 256;    // [NA,512] KM_writes
  bf16* km_p = km_a + (size_t)kNA * 512;  // [NP,512] KM_cites then KM_wb
  float* tr_a = (float*)R;                // fp32 view, disjoint lifetime
  float* tr_p = tr_a + (size_t)kNA * 256;
  char* afterR = R + ((size_t)(kNA + kNP) * 256 + (size_t)(kNA + kNP) * 512) * sizeof(bf16);
  bf16* agg_a = (bf16*)afterR;
  bf16* agg_p = agg_a + (size_t)kNA * 256;

  const bf16* c_ew_wb = canon + kOff(0);
  const bf16* c_ew_w  = canon + kOff(1);
  const bf16* c_ew_c  = canon + kOff(2);
  const bf16* c_adW   = canon + kOff(3);
  const bf16* c_adb   = canon + kOff(4);
  const bf16* c_kW    = canon + kOff(5);
  const bf16* c_kb    = canon + kOff(6);
  const bf16* c_qW    = canon + kOff(7);
  const bf16* c_qb    = canon + kOff(8);
  const bf16* c_mW    = canon + kOff(9);
  const bf16* c_mb    = canon + kOff(10);
  const bf16* c_aW    = canon + kOff(11);
  const bf16* c_ab    = canon + kOff(12);
  const bf16* c_wpri  = canon + kOff(13);
  const bf16* c_watt  = canon + kOff(14);
  const bf16* c_wmsg  = canon + kOff(15);
  const bf16* c_skip  = canon + kOff(16);
  const bf16* c_lng   = canon + kOff(17);
  const bf16* c_lnb   = canon + kOff(18);
  const bf16* c_outW  = canon + kOff(19);
  const bf16* c_outb  = canon + kOff(20);

  const unsigned* fIn = flags + 0;
  const unsigned* f1  = flags + 1;

  detect_dtype<<<1, 256, 0, stream>>>((const unsigned*)d_in[0], flags);

  CanonArgs ca;
  for (int s = 0; s < kNSeg; ++s) { ca.n[s] = kSegN[s]; ca.dstOff[s] = (unsigned)kOff(s); }
  const int srcIdx[kNSeg] = {2,3,4, 5,6, 7,8, 9,10, 11,12, 13,14, 15, 16,17, 18,19,20, 21,22};
  for (int s = 0; s < kNSeg; ++s) ca.src[s] = d_in[srcIdx[s]];
  canon_kernel<<<dim3(1172, kNSeg), 256, 0, stream>>>(ca, canon, flags);

  TransArgs ta;
  ta.src[0] = c_adW;              ta.dst[0] = adWT;
  ta.src[1] = c_adW + 65536;      ta.dst[1] = adWT + 65536;
  for (int m = 0; m < 4; ++m) { ta.src[2 + m] = c_qW + (size_t)m * 65536; ta.dst[2 + m] = qWT + (size_t)m * 65536; }
  for (int m = 0; m < 4; ++m) { ta.src[6 + m] = c_aW + (size_t)m * 65536; ta.dst[6 + m] = aWT + (size_t)m * 65536; }
  transpose_w<<<dim3(4, 4, 10), 256, 0, stream>>>(ta);

  // ---- CSR build (fused hist + 3-level scan + fused scatter) ----
  hipMemsetAsync(cur_wb, 0, (size_t)((kNA + 1) + 2 * (kNP + 1)) * 4, stream);
  HistArgs ha;
  ha.dst[0] = dst_wb; ha.cnt[0] = cur_wb; ha.E[0] = kEWB;
  ha.dst[1] = dst_w;  ha.cnt[1] = cur_w;  ha.E[1] = kEW;
  ha.dst[2] = dst_c;  ha.cnt[2] = cur_c;  ha.E[2] = kEC;
  csr_hist<<<dim3((kEC + 255) / 256, 3), 256, 0, stream>>>(ha);
  ScanArgs sa;
  sa.deg[0] = cur_wb;  sa.offs[0] = offs_wb; sa.N[0] = kNA;
  sa.deg[1] = cur_w;   sa.offs[1] = offs_w;  sa.N[1] = kNP;
  sa.deg[2] = cur_c;   sa.offs[2] = offs_c;  sa.N[2] = kNP;
  sa.bsums = bsums;
  scan_l1<<<dim3(32, 3), 256, 0, stream>>>(sa);
  scan_l2<<<3, 64, 0, stream>>>(bsums, totals);
  scan_l3<<<dim3(20, 3), 256, 0, stream>>>(sa, totals);
  ScatArgs sc;
  sc.dst[0] = dst_wb; sc.src[0] = src_wb; sc.ew[0] = c_ew_wb; sc.cur[0] = cur_wb;
  sc.srcs[0] = srcs_wb; sc.ews[0] = ews_wb; sc.E[0] = kEWB;
  sc.dst[1] = dst_w;  sc.src[1] = src_w;  sc.ew[1] = c_ew_w;  sc.cur[1] = cur_w;
  sc.srcs[1] = srcs_w;  sc.ews[1] = ews_w;  sc.E[1] = kEW;
  sc.dst[2] = dst_c;  sc.src[2] = src_c;  sc.ew[2] = c_ew_c;  sc.cur[2] = cur_c;
  sc.srcs[2] = srcs_c;  sc.ews[2] = ews_c;  sc.E[2] = kEC;
  csr_scatter<<<dim3((kEC + 255) / 256, 3), 256, 0, stream>>>(sc);

  combine_weights<<<dim3(8, 24), 256, 0, stream>>>(c_kW, c_kb, c_watt, KMeffT, kmbeT, 0);
  combine_weights<<<dim3(8, 24), 256, 0, stream>>>(c_mW, c_mb, c_wmsg, KMeffT, kmbeT, 256);

  const int ntA = (kNA + 127) / 128;   // 157
  const int ntP = (kNP + 127) / 128;   // 313
  auto sgrid = [](int maxnt, int nslab) {
    return dim3((unsigned)(((maxnt + 7) / 8) * 8 * nslab));
  };
  auto mkd = [](const bf16* wt, const bf16* bias, const void* A, void* c,
                int ldc, int coff, int act, int otype, int M, int ntiles) {
    GemmDesc g;
    g.wt = (const short*)wt; g.bias = bias; g.A = A; g.c = c; g.ldc = ldc;
    g.coff = coff; g.act = act; g.otype = otype; g.M = M; g.ntiles = ntiles;
    return g;
  };

  // adapt (fused authors+papers): feats = gelu(x @ adapt_W + b)
  {
    MultiDesc md{};
    md.d[0] = mkd(adWT,                 c_adb,       d_in[0], fa,  256, 0,   1, 0, kNA, ntA);
    md.d[1] = mkd(adWT + 128 * 256,     c_adb + 128, d_in[0], fa,  256, 128, 1, 0, kNA, ntA);
    md.d[2] = mkd(adWT + 65536,         c_adb + 256, d_in[1], fp_, 256, 0,   1, 0, kNP, ntP);
    md.d[3] = mkd(adWT + 65536 + 128 * 256, c_adb + 384, d_in[1], fp_, 256, 128, 1, 0, kNP, ntP);
    mfma_gemm128<<<sgrid(ntP, 4), 256, 0, stream>>>(fIn, md, 4);
  }

  for (int l = 0; l < 2; ++l) {
    const bf16* qW_a = qWT + (size_t)(l * 2 + 0) * 65536;
    const bf16* qW_p = qWT + (size_t)(l * 2 + 1) * 65536;
    const bf16* qb_a = c_qb + (l * 2 + 0) * 256;
    const bf16* qb_p = c_qb + (l * 2 + 1) * 256;
    const bf16* KM_c  = KMeffT + (size_t)(l * 3 + 0) * 512 * 256;
    const bf16* KM_w  = KMeffT + (size_t)(l * 3 + 1) * 512 * 256;
    const bf16* KM_wb = KMeffT + (size_t)(l * 3 + 2) * 512 * 256;
    const bf16* kb_c  = kmbeT + (l * 3 + 0) * 512;
    const bf16* kb_w  = kmbeT + (l * 3 + 1) * 512;
    const bf16* kb_wb = kmbeT + (l * 3 + 2) * 512;

    // (1) papers-proj phase 1: Q_p (2) + KM_cites (4) -> qp, km_p
    {
      MultiDesc md{};
      md.d[0] = mkd(qW_p,             qb_p,       fp_, qp,   256, 0,   0, 0, kNP, ntP);
      md.d[1] = mkd(qW_p + 128 * 256, qb_p + 128, fp_, qp,   256, 128, 0, 0, kNP, ntP);
      for (int s = 0; s < 4; ++s)
        md.d[2 + s] = mkd(KM_c + (size_t)s * 128 * 256, kb_c + s * 128, fp_, km_p, 512, s * 128, 0, 0, kNP, ntP);
      mfma_gemm128<<<sgrid(ntP, 6), 256, 0, stream>>>(f1, md, 6);
    }
    // (2) CITES gather: agg_p = 0.5 * cites_sum
    {
      GatherDesc dc{qp, km_p, srcs_c, ews_c, offs_c, c_wpri + (l * 3 + 0) * 4,
                    agg_p, kNP, 0, 0.5f};
      GatherDesc dz{}; dz.Nd = 0;
      gather_fused<<<(kNP + 3) / 4, 256, 0, stream>>>(dc, dz, (kNP + 3) / 4);
    }
    // (3) mixed proj: Q_a (2) + KM_writes (4) from fa; KM_wb (4) from fp_
    //     (overwrites km_p; safe after (2) by stream order)
    {
      MultiDesc md{};
      md.d[0] = mkd(qW_a,             qb_a,       fa, qa,   256, 0,   0, 0, kNA, ntA);
      md.d[1] = mkd(qW_a + 128 * 256, qb_a + 128, fa, qa,   256, 128, 0, 0, kNA, ntA);
      for (int s = 0; s < 4; ++s)
        md.d[2 + s] = mkd(KM_w + (size_t)s * 128 * 256, kb_w + s * 128, fa, km_a, 512, s * 128, 0, 0, kNA, ntA);
      for (int s = 0; s < 4; ++s)
        md.d[6 + s] = mkd(KM_wb + (size_t)s * 128 * 256, kb_wb + s * 128, fp_, km_p, 512, s * 128, 0, 0, kNP, ntP);
      mfma_gemm128<<<sgrid(ntP, 10), 256, 0, stream>>>(f1, md, 10);
    }
    // (4) fused WB (->agg_a) + WRITES (agg_p += 0.5*writes_sum)
    {
      GatherDesc dwb{qa, km_p, srcs_wb, ews_wb, offs_wb, c_wpri + (l * 3 + 2) * 4,
                     agg_a, kNA, 0, 1.f};
      GatherDesc dw{qp, km_a, srcs_w, ews_w, offs_w, c_wpri + (l * 3 + 1) * 4,
                    agg_p, kNP, 1, 0.5f};
      const int bA = (kNA + 3) / 4;
      gather_fused<<<bA + (kNP + 3) / 4, 256, 0, stream>>>(dwb, dw, bA);
    }
    // (5) fused A-projection (authors + papers) -> fp32 tr
    {
      const bf16* aW_a = aWT + (size_t)(l * 2 + 0) * 65536;
      const bf16* aW_p = aWT + (size_t)(l * 2 + 1) * 65536;
      MultiDesc md{};
      md.d[0] = mkd(aW_a,             c_ab + (l * 2 + 0) * 256,       agg_a, tr_a, 256, 0,   0, 1, kNA, ntA);
      md.d[1] = mkd(aW_a + 128 * 256, c_ab + (l * 2 + 0) * 256 + 128, agg_a, tr_a, 256, 128, 0, 1, kNA, ntA);
      md.d[2] = mkd(aW_p,             c_ab + (l * 2 + 1) * 256,       agg_p, tr_p, 256, 0,   0, 1, kNP, ntP);
      md.d[3] = mkd(aW_p + 128 * 256, c_ab + (l * 2 + 1) * 256 + 128, agg_p, tr_p, 256, 128, 0, 1, kNP, ntP);
      mfma_gemm128<<<sgrid(ntP, 4), 256, 0, stream>>>(f1, md, 4);
    }
    // (6) fused skip+LN
    skip_ln2<<<(kNA + kNP) / 4, 256, 0, stream>>>(
        tr_a, fa,  c_skip + l * 3 + 0, c_lng + (l * 2 + 0) * 256, c_lnb + (l * 2 + 0) * 256,
        tr_p, fp_, c_skip + l * 3 + 1, c_lng + (l * 2 + 1) * 256, c_lnb + (l * 2 + 1) * 256,
        kNA, kNA + kNP);
  }

  out_gemm<<<kNP / 64, 256, 0, stream>>>(fp_, c_outW, c_outb, d_out, fIn, kNP);
}

// Round 13
// 823.162 us; speedup vs baseline: 1.2650x; 1.0373x over previous
//
#include <hip/hip_runtime.h>
#include <hip/hip_bf16.h>
#include <math.h>

using bf16 = __hip_bfloat16;

typedef __attribute__((ext_vector_type(8))) short short8;   // 8 bf16 (4 VGPRs)
typedef __attribute__((ext_vector_type(4))) float float4v;  // MFMA acc

static constexpr int kNA  = 20000;
static constexpr int kNP  = 40000;
static constexpr int kEWB = 150000;
static constexpr int kEW  = 150000;
static constexpr int kEC  = 300000;

// ---- canonical bf16 input region ----
static constexpr int kNSeg = 21;
static constexpr int kSegN[kNSeg] = {
  150000, 150000, 300000,           // ew_wb, ew_w, ew_c
  131072, 512,                      // adW, adb
  262144, 1024,                     // kW, kb
  262144, 1024,                     // qW, qb
  262144, 1024,                     // mW, mb
  262144, 1024,                     // aW, ab
  24,                               // wpri
  98304, 98304,                     // watt, wmsg
  6, 1024, 1024,                    // skip, lng, lnb
  16384, 64                         // outW, outb
};
static constexpr size_t kOff(int s) {
  size_t o = 0;
  for (int i = 0; i < s; ++i) o += (size_t)kSegN[i];
  return o;
}
static constexpr size_t kCanonTotal = kOff(kNSeg);

struct CanonArgs {
  const void* src[kNSeg];
  int n[kNSeg];
  unsigned dstOff[kNSeg];
};
struct TransArgs {
  const bf16* src[10];
  bf16* dst[10];
};
// per-slab GEMM descriptor (slab = 128 output cols); per-slab A/M/ntiles
struct GemmDesc {
  const short* wt;   // [128][256] n-major slab
  const bf16* bias;  // 128 entries (slab-local)
  const void* A;     // input activations
  void* c;           // output base
  int ldc;
  int coff;
  int act;           // 1 = gelu
  int otype;         // 0 = bf16, 1 = fp32
  int M;
  int ntiles;        // ceil(M/128)
};
struct MultiDesc { GemmDesc d[16]; };
// three-relation scan / hist / scatter descriptors
struct ScanArgs {
  int* deg[3];
  int* offs[3];
  int* bsums;
  int N[3];
};
struct HistArgs {
  const int* dst[3];
  int* cnt[3];
  int E[3];
};
struct ScatArgs {
  const int* dst[3];
  const int* src[3];
  const bf16* ew[3];
  int* cur[3];
  int* srcs[3];
  bf16* ews[3];
  int E[3];
};
// tri-relation gather descriptor (authors: wb; papers: cites + writes)
struct TriDesc {
  const bf16* qa; const bf16* qp;
  const bf16* km_wb;  // [NP,512] wb-transformed papers
  const bf16* km_c;   // [NP,512] cites-transformed papers
  const bf16* km_w;   // [NA,512] writes-transformed authors
  const int* srcs_wb; const int* srcs_c; const int* srcs_w;
  const bf16* ews_wb; const bf16* ews_c; const bf16* ews_w;
  const int* offs_wb; const int* offs_c; const int* offs_w;
  const bf16* pri_wb; const bf16* pri_c; const bf16* pri_w;
  bf16* agg_a; bf16* agg_p;
};

__device__ __forceinline__ float toF(float x) { return x; }
__device__ __forceinline__ float toF(bf16 x)  { return __bfloat162float(x); }
__device__ __forceinline__ float bits2f(unsigned short b) {
  unsigned int u = ((unsigned int)b) << 16;
  return __uint_as_float(u);
}
__device__ __forceinline__ float sigmoidf_(float x) { return 1.0f / (1.0f + expf(-x)); }
__device__ __forceinline__ float gelu_exact(float x) {
  return 0.5f * x * (1.0f + erff(x * 0.70710678118654752f));
}

// -------------------------------------------------------------------------
__global__ __launch_bounds__(256) void detect_dtype(
    const unsigned* __restrict__ x, unsigned* __restrict__ flags)
{
  __shared__ int cnt;
  if (threadIdx.x == 0) cnt = 0;
  __syncthreads();
  unsigned w = x[threadIdx.x];
  unsigned e = (w >> 7) & 0xFFu;
  if (e >= 110u && e <= 140u) atomicAdd(&cnt, 1);
  __syncthreads();
  if (threadIdx.x == 0) {
    flags[0] = (cnt >= 128) ? 1u : 0u;
    flags[1] = 1u;
  }
}

__global__ __launch_bounds__(256) void canon_kernel(
    CanonArgs a, bf16* __restrict__ dst, const unsigned* __restrict__ flags)
{
  const int s = blockIdx.y;
  const int i = blockIdx.x * 256 + threadIdx.x;
  if (i >= a.n[s]) return;
  bf16 v;
  if (flags[0]) v = ((const bf16*)a.src[s])[i];
  else          v = __float2bfloat16(((const float*)a.src[s])[i]);
  dst[a.dstOff[s] + i] = v;
}

// -------------------------------------------------------------------------
__global__ __launch_bounds__(256) void transpose_w(TransArgs ta)
{
  const int m = blockIdx.z;
  const short* src = (const short*)ta.src[m];
  short* dst = (short*)ta.dst[m];
  const int k0 = blockIdx.x * 64, n0 = blockIdx.y * 64;
  __shared__ short tile[64][65];
  const int tx = threadIdx.x & 63, ty = threadIdx.x >> 6;
  for (int i = ty; i < 64; i += 4)
    tile[i][tx] = src[(size_t)(k0 + i) * 256 + n0 + tx];
  __syncthreads();
  for (int i = ty; i < 64; i += 4)
    dst[(size_t)(n0 + i) * 256 + k0 + tx] = tile[tx][i];
}

// -------------------------------------------------------------------------
// CSR build: fused histogram -> 3-level parallel scan -> fused scatter.
// -------------------------------------------------------------------------
__global__ __launch_bounds__(256) void csr_hist(HistArgs h)
{
  const int rel = blockIdx.y;
  const int i = blockIdx.x * 256 + threadIdx.x;
  if (i < h.E[rel]) atomicAdd(&h.cnt[rel][h.dst[rel][i]], 1);
}

__global__ __launch_bounds__(256) void scan_l1(ScanArgs a)
{
  const int rel = blockIdx.y;
  const int N = a.N[rel];
  const int t = threadIdx.x;
  const int lane = t & 63;
  const int wid = t >> 6;
  const int i0 = blockIdx.x * 2048 + t * 8;
  const int* deg = a.deg[rel];
  int v[8];
  int T = 0;
  #pragma unroll
  for (int j = 0; j < 8; ++j) {
    v[j] = (i0 + j < N) ? deg[i0 + j] : 0;
    T += v[j];
  }
  int incl = T;
  #pragma unroll
  for (int off = 1; off < 64; off <<= 1) {
    const int u = __shfl_up(incl, off);
    if (lane >= off) incl += u;
  }
  __shared__ int wsum[4];
  if (lane == 63) wsum[wid] = incl;
  __syncthreads();
  int woff = 0;
  #pragma unroll
  for (int wp = 0; wp < 4; ++wp) if (wp < wid) woff += wsum[wp];
  int run = woff + incl - T;
  int* offs = a.offs[rel];
  #pragma unroll
  for (int j = 0; j < 8; ++j) {
    if (i0 + j < N) offs[i0 + j] = run;
    run += v[j];
  }
  if (t == 0)
    a.bsums[rel * 32 + blockIdx.x] = wsum[0] + wsum[1] + wsum[2] + wsum[3];
}

__global__ __launch_bounds__(64) void scan_l2(int* __restrict__ bsums,
                                              int* __restrict__ totals)
{
  const int rel = blockIdx.x;
  const int lane = threadIdx.x;
  const int v = (lane < 32) ? bsums[rel * 32 + lane] : 0;
  int incl = v;
  #pragma unroll
  for (int off = 1; off < 64; off <<= 1) {
    const int u = __shfl_up(incl, off);
    if (lane >= off) incl += u;
  }
  if (lane < 32) bsums[rel * 32 + lane] = incl - v;
  if (lane == 63) totals[rel] = incl;
}

__global__ __launch_bounds__(256) void scan_l3(ScanArgs a,
                                               const int* __restrict__ totals)
{
  const int rel = blockIdx.y;
  const int N = a.N[rel];
  const int i0 = blockIdx.x * 2048 + threadIdx.x * 8;
  const int boff = a.bsums[rel * 32 + blockIdx.x];
  int* offs = a.offs[rel];
  int* cur = a.deg[rel];
  #pragma unroll
  for (int j = 0; j < 8; ++j) {
    const int idx = i0 + j;
    if (idx < N) {
      const int o = offs[idx] + boff;
      offs[idx] = o;
      cur[idx] = o;
    }
  }
  if (blockIdx.x == 0 && threadIdx.x == 0) offs[N] = totals[rel];
}

__global__ __launch_bounds__(256) void csr_scatter(ScatArgs s)
{
  const int rel = blockIdx.y;
  const int i = blockIdx.x * 256 + threadIdx.x;
  if (i >= s.E[rel]) return;
  const int p = atomicAdd(&s.cur[rel][s.dst[rel][i]], 1);
  s.srcs[rel][p] = s.src[rel][i];
  s.ews[rel][p]  = s.ew[rel][i];
}

// -------------------------------------------------------------------------
// Fold per-head w_att/w_msg into K/M projections; emit fused-transposed
// KMT[l,e][512][256] bf16 + bias kmb[l,e][512]. grid (8, 24).
// -------------------------------------------------------------------------
__global__ __launch_bounds__(256) void combine_weights(
    const bf16* __restrict__ Wbig, const bf16* __restrict__ bbig,
    const bf16* __restrict__ wsm, bf16* __restrict__ KMT,
    bf16* __restrict__ kmb, int noff)
{
  const int blk = blockIdx.y;
  const int rc  = blockIdx.x;
  const int h = blk & 3;
  const int le = blk >> 2;
  const int e = le % 3;
  const int l = le / 3;
  const int st = (e == 1) ? 0 : 1;

  const short* Wsrc = (const short*)(Wbig + (size_t)(l * 2 + st) * 65536);
  const bf16*  bsrc = bbig + (size_t)(l * 2 + st) * 256;
  const short* wm   = (const short*)(wsm + ((size_t)(l * 3 + e) * 4 + h) * 4096);
  short* outT = (short*)(KMT + (size_t)(l * 3 + e) * 512 * 256);
  bf16* outb  = kmb + (size_t)(l * 3 + e) * 512;

  __shared__ short w[64][72];
  __shared__ short As[32][72];
  __shared__ short ot[64][40];

  const int t = threadIdx.x;
  {
    const int base = t * 16;
    const int r0 = base >> 6, c0 = base & 63;
    *(short8*)&w[r0][c0]     = *(const short8*)&wm[base];
    *(short8*)&w[r0][c0 + 8] = *(const short8*)&wm[base + 8];
  }
  {
    const int row = t >> 3;
    const int kc = (t & 7) * 8;
    *(short8*)&As[row][kc] =
        *(const short8*)&Wsrc[(size_t)(rc * 32 + row) * 256 + h * 64 + kc];
  }
  __syncthreads();

  const int j   = t & 63;
  const int sub = t >> 6;
  float accv[8] = {};
  #pragma unroll
  for (int d = 0; d < 64; ++d) {
    const float wd = bits2f((unsigned short)w[d][j]);
    #pragma unroll
    for (int r8 = 0; r8 < 8; ++r8)
      accv[r8] += bits2f((unsigned short)As[sub * 8 + r8][d]) * wd;
  }
  #pragma unroll
  for (int r8 = 0; r8 < 8; ++r8) {
    union { bf16 h; short s; } cv;
    cv.h = __float2bfloat16(accv[r8]);
    ot[j][sub * 8 + r8] = cv.s;
  }

  if (rc == 0 && t < 64) {
    float acc = 0.f;
    #pragma unroll
    for (int d = 0; d < 64; ++d)
      acc += toF(bsrc[h * 64 + d]) * bits2f((unsigned short)w[d][t]);
    outb[h * 64 + t + noff] = __float2bfloat16(acc);
  }
  __syncthreads();
  {
    const int nn = t >> 2;
    const int kx = (t & 3) * 8;
    short8 v;
    #pragma unroll
    for (int x = 0; x < 8; ++x) v[x] = ot[nn][kx + x];
    *(short8*)&outT[(size_t)(h * 64 + nn + noff) * 256 + rc * 32 + kx] = v;
  }
}

// -------------------------------------------------------------------------
// Multi-output MFMA GEMM with per-slab A/M/ntiles. Tile 128x128, BK=64,
// 4 waves in 2x2. XCD swizzle: same-tile blocks 8 apart -> same XCD
// [measured r11: FETCH 63->21.7 MB on papers-proj].
// -------------------------------------------------------------------------
__global__ __launch_bounds__(256, 4) void mfma_gemm128(
    const unsigned* __restrict__ aflag, MultiDesc md, int nslab)
{
  __shared__ short As[128][72];
  __shared__ short Bs[128][72];
  const int lid = blockIdx.x;
  const int grp = lid / (8 * nslab);
  const int rem = lid - grp * 8 * nslab;
  const int slab = rem >> 3;
  const int tx = grp * 8 + (rem & 7);
  const GemmDesc d = md.d[slab];
  if (tx >= d.ntiles) return;
  const bool abf = (*aflag != 0u);
  const int M = d.M;
  const int t = threadIdx.x;
  const int bm = tx * 128;
  const int lane = t & 63;
  const int wid  = t >> 6;
  const int wm = (wid >> 1) * 64;
  const int wn = (wid & 1) * 64;
  const int col16 = lane & 15;
  const int quad  = lane >> 4;
  const int rr = t >> 3;
  const int kk = (t & 7) * 8;

  float4v acc[4][4];
  #pragma unroll
  for (int mi = 0; mi < 4; ++mi)
    #pragma unroll
    for (int ni = 0; ni < 4; ++ni) acc[mi][ni] = (float4v){0.f, 0.f, 0.f, 0.f};

  for (int k0 = 0; k0 < 256; k0 += 64) {
    #pragma unroll
    for (int it = 0; it < 4; ++it) {
      const int row = it * 32 + rr;
      const int grow = bm + row;
      short8 v = (short8){0, 0, 0, 0, 0, 0, 0, 0};
      if (grow < M) {
        if (abf) {
          v = *(const short8*)((const short*)d.A + (size_t)grow * 256 + k0 + kk);
        } else {
          const float* ap = (const float*)d.A + (size_t)grow * 256 + k0 + kk;
          #pragma unroll
          for (int j = 0; j < 8; ++j) {
            union { bf16 h; short s; } cv;
            cv.h = __float2bfloat16(ap[j]);
            v[j] = cv.s;
          }
        }
      }
      *(short8*)&As[row][kk] = v;
    }
    #pragma unroll
    for (int it = 0; it < 4; ++it) {
      const int n = it * 32 + rr;
      *(short8*)&Bs[n][kk] = *(const short8*)&d.wt[(size_t)n * 256 + k0 + kk];
    }
    __syncthreads();

    #pragma unroll
    for (int ks = 0; ks < 64; ks += 32) {
      short8 bfr[4];
      #pragma unroll
      for (int ni = 0; ni < 4; ++ni)
        bfr[ni] = *(const short8*)&Bs[wn + ni * 16 + col16][ks + quad * 8];
      #pragma unroll
      for (int mi = 0; mi < 4; ++mi) {
        const short8 afr = *(const short8*)&As[wm + mi * 16 + col16][ks + quad * 8];
        #pragma unroll
        for (int ni = 0; ni < 4; ++ni)
          acc[mi][ni] = __builtin_amdgcn_mfma_f32_16x16x32_bf16(afr, bfr[ni], acc[mi][ni], 0, 0, 0);
      }
    }
    __syncthreads();
  }

  #pragma unroll
  for (int ni = 0; ni < 4; ++ni) {
    const int col = wn + ni * 16 + col16;
    const float bc = toF(d.bias[col]);
    const int gcol = d.coff + col;
    #pragma unroll
    for (int mi = 0; mi < 4; ++mi) {
      #pragma unroll
      for (int r = 0; r < 4; ++r) {
        const int row = bm + wm + mi * 16 + quad * 4 + r;
        if (row < M) {
          float v = acc[mi][ni][r] + bc;
          if (d.act == 1) v = gelu_exact(v);
          const size_t idx = (size_t)row * d.ldc + gcol;
          if (d.otype == 0) ((bf16*)d.c)[idx] = __float2bfloat16(v);
          else              ((float*)d.c)[idx] = v;
        }
      }
    }
  }
}

// -------------------------------------------------------------------------
// Tri-relation gather: author blocks do WB -> agg_a; paper blocks do
// CITES + WRITES accumulated in registers in ONE pass -> agg_p (0.5 mean,
// no read-back). Split-wave halves, 16B loads, 8-lane head reduction.
// -------------------------------------------------------------------------
__device__ __forceinline__ void gather_loop(
    const float qf[8], const bf16* km, const int* srcs, const bf16* ews,
    int beg, int end, int h, int sl, float prih, float acc[8])
{
  union B8 { uint4 u; unsigned short s[8]; };
  for (int idx = beg + h; idx < end; idx += 2) {
    const int s = srcs[idx];
    const float w = toF(ews[idx]);
    B8 kb;
    kb.u = ((const uint4*)(km + (size_t)s * 512))[sl];
    float dot = 0.f;
    #pragma unroll
    for (int j = 0; j < 8; ++j) dot += qf[j] * bits2f(kb.s[j]);
    dot += __shfl_xor(dot, 1);
    dot += __shfl_xor(dot, 2);
    dot += __shfl_xor(dot, 4);
    const float a = w * sigmoidf_(dot * prih * 0.125f);
    B8 mb;
    mb.u = ((const uint4*)(km + (size_t)s * 512 + 256))[sl];
    #pragma unroll
    for (int j = 0; j < 8; ++j) acc[j] += bits2f(mb.s[j]) * a;
  }
}

__global__ __launch_bounds__(256) void tri_gather(TriDesc td, int bA)
{
  const bool isA = (blockIdx.x < (unsigned)bA);
  const int bidx = isA ? blockIdx.x : blockIdx.x - bA;
  const int lane = threadIdx.x & 63;
  const int wid  = threadIdx.x >> 6;
  const int node = bidx * 4 + wid;
  const int Nd = isA ? kNA : kNP;
  if (node >= Nd) return;
  const int h  = lane >> 5;
  const int sl = lane & 31;

  union B8 { uint4 u; unsigned short s[8]; };
  const bf16* q = isA ? td.qa : td.qp;
  B8 qv;
  qv.u = ((const uint4*)(q + (size_t)node * 256))[sl];
  float qf[8];
  #pragma unroll
  for (int j = 0; j < 8; ++j) qf[j] = bits2f(qv.s[j]);

  float acc[8] = {};
  float scale;
  bf16* aggout;
  if (isA) {
    gather_loop(qf, td.km_wb, td.srcs_wb, td.ews_wb,
                td.offs_wb[node], td.offs_wb[node + 1], h, sl,
                toF(td.pri_wb[sl >> 3]), acc);
    scale = 1.f;
    aggout = td.agg_a;
  } else {
    gather_loop(qf, td.km_c, td.srcs_c, td.ews_c,
                td.offs_c[node], td.offs_c[node + 1], h, sl,
                toF(td.pri_c[sl >> 3]), acc);
    gather_loop(qf, td.km_w, td.srcs_w, td.ews_w,
                td.offs_w[node], td.offs_w[node + 1], h, sl,
                toF(td.pri_w[sl >> 3]), acc);
    scale = 0.5f;
    aggout = td.agg_p;
  }

  #pragma unroll
  for (int j = 0; j < 8; ++j) acc[j] += __shfl_xor(acc[j], 32);

  if (h == 0) {
    B8 ov;
    #pragma unroll
    for (int j = 0; j < 8; ++j) {
      union { bf16 h; unsigned short u; } cv;
      cv.h = __float2bfloat16(acc[j] * scale);
      ov.s[j] = cv.u;
    }
    *(uint4*)(aggout + (size_t)node * 256 + sl * 8) = ov.u;
  }
}

// -------------------------------------------------------------------------
// Fused skip+LN over both node types: node-range decode. One wave per node.
// -------------------------------------------------------------------------
__global__ __launch_bounds__(256) void skip_ln2(
    const float* __restrict__ trA, bf16* __restrict__ featA,
    const bf16* __restrict__ skA, const bf16* __restrict__ gA_, const bf16* __restrict__ bA,
    const float* __restrict__ trP, bf16* __restrict__ featP,
    const bf16* __restrict__ skP, const bf16* __restrict__ gP, const bf16* __restrict__ bP,
    int NA, int Ntot)
{
  const int lane = threadIdx.x & 63;
  const int wid  = threadIdx.x >> 6;
  int node = blockIdx.x * 4 + wid;
  if (node >= Ntot) return;
  const float* tr; bf16* feat; const bf16 *sk, *g, *b;
  if (node < NA) { tr = trA; feat = featA; sk = skA; g = gA_; b = bA; }
  else { node -= NA; tr = trP; feat = featP; sk = skP; g = gP; b = bP; }

  const float alpha = sigmoidf_(toF(*sk));
  const float4 t = ((const float4*)(tr + (size_t)node * 256))[lane];
  union B4 { uint2 u; unsigned short s[4]; };
  B4 fb;
  fb.u = ((const uint2*)(feat + (size_t)node * 256))[lane];
  float o[4];
  o[0] = t.x * alpha + bits2f(fb.s[0]) * (1.f - alpha);
  o[1] = t.y * alpha + bits2f(fb.s[1]) * (1.f - alpha);
  o[2] = t.z * alpha + bits2f(fb.s[2]) * (1.f - alpha);
  o[3] = t.w * alpha + bits2f(fb.s[3]) * (1.f - alpha);

  float sum = o[0] + o[1] + o[2] + o[3];
  #pragma unroll
  for (int off = 32; off; off >>= 1) sum += __shfl_xor(sum, off);
  const float mu = sum * (1.f / 256.f);

  float dd[4], sq = 0.f;
  #pragma unroll
  for (int j = 0; j < 4; ++j) { dd[j] = o[j] - mu; sq += dd[j] * dd[j]; }
  #pragma unroll
  for (int off = 32; off; off >>= 1) sq += __shfl_xor(sq, off);
  const float rs = rsqrtf(sq * (1.f / 256.f) + 1e-5f);

  bf16* fout = feat + (size_t)node * 256 + lane * 4;
  #pragma unroll
  for (int j = 0; j < 4; ++j) {
    float r = dd[j] * rs * toF(g[lane * 4 + j]) + toF(b[lane * 4 + j]);
    fout[j] = __float2bfloat16(r);
  }
}

// -------------------------------------------------------------------------
// out[M,64] = A[M,256] @ W[256,64] + b[64]; output dtype per *flag.
// -------------------------------------------------------------------------
__global__ __launch_bounds__(256) void out_gemm(
    const bf16* __restrict__ A, const bf16* __restrict__ W,
    const bf16* __restrict__ bias, void* __restrict__ out,
    const unsigned* __restrict__ flag, int M)
{
  __shared__ float Ws[64][64];
  const bool obf = (*flag != 0u);
  const int tid = threadIdx.x;
  const int row = blockIdx.x * 64 + (tid >> 2);
  const int c0 = (tid & 3) * 16;
  const int arow = (row < M) ? row : 0;
  const bf16* a = A + (size_t)arow * 256;
  float acc[16] = {};
  for (int k0 = 0; k0 < 256; k0 += 64) {
    for (int i = tid; i < 4096; i += 256)
      Ws[i >> 6][i & 63] = toF(W[(size_t)(k0 + (i >> 6)) * 64 + (i & 63)]);
    __syncthreads();
    for (int k = 0; k < 64; ++k) {
      const float av = toF(a[k0 + k]);
      #pragma unroll
      for (int j = 0; j < 16; ++j) acc[j] += av * Ws[k][c0 + j];
    }
    __syncthreads();
  }
  if (row < M) {
    #pragma unroll
    for (int j = 0; j < 16; ++j) {
      const float v = acc[j] + toF(bias[c0 + j]);
      const size_t idx = (size_t)row * 64 + c0 + j;
      if (obf) ((bf16*)out)[idx] = __float2bfloat16(v);
      else     ((float*)out)[idx] = v;
    }
  }
}

// -------------------------------------------------------------------------
extern "C" void kernel_launch(void* const* d_in, const int* in_sizes, int n_in,
                              void* d_out, int out_size, void* d_ws, size_t ws_size,
                              hipStream_t stream) {
  const int* src_wb  = (const int*)d_in[23];
  const int* dst_wb  = (const int*)d_in[24];
  const int* src_w   = (const int*)d_in[25];
  const int* dst_w   = (const int*)d_in[26];
  const int* src_c   = (const int*)d_in[27];
  const int* dst_c   = (const int*)d_in[28];

  // ---- workspace carve (~204 MB total; r0 crash at 272 MB is the only
  //      known upper bound, consistent with a 256 MiB ws) ----
  char* base = (char*)d_ws;
  unsigned* flags = (unsigned*)base;
  bf16* canon = (bf16*)(base + 256);
  char* p = base + 256 + (((size_t)kCanonTotal * 2 + 511) & ~(size_t)511);
  bf16* adWT = (bf16*)p;
  bf16* qWT  = adWT + (size_t)2 * 65536;
  bf16* aWT  = qWT  + (size_t)4 * 65536;
  bf16* KMeffT = aWT + (size_t)4 * 65536;    // 6 x 512*256
  bf16* kmbeT  = KMeffT + (size_t)6 * 512 * 256;
  char* pc = (char*)(((size_t)(kmbeT + 6 * 512) + 511) & ~(size_t)511);
  int* cur_wb  = (int*)pc;
  int* cur_w   = cur_wb + (kNA + 1);
  int* cur_c   = cur_w + (kNP + 1);
  int* offs_wb = cur_c + (kNP + 1);
  int* offs_w  = offs_wb + (kNA + 1);
  int* offs_c  = offs_w + (kNP + 1);
  int* srcs_wb = offs_c + (kNP + 1);
  int* srcs_w  = srcs_wb + kEWB;
  int* srcs_c  = srcs_w + kEW;
  bf16* ews_wb = (bf16*)(srcs_c + kEC);
  bf16* ews_w  = ews_wb + kEWB;
  bf16* ews_c  = ews_w + kEW;
  int* bsums   = (int*)(ews_c + kEC);
  int* totals  = bsums + 96;
  char* p2 = (char*)(((size_t)(totals + 3) + 511) & ~(size_t)511);
  bf16* fa  = (bf16*)p2;
  bf16* fp_ = fa + (size_t)kNA * 256;
  char* R   = (char*)(fp_ + (size_t)kNP * 256);
  bf16* qa    = (bf16*)R;                   // [NA,256]
  bf16* qp    = qa + (size_t)kNA * 256;     // [NP,256]
  bf16* km_a  = qp + (size_t)kNP * 256;     // [NA,512] writes-KM
  bf16* km_cp = km_a + (size_t)kNA * 512;   // [NP,512] cites-KM
  bf16* km_wbp= km_cp + (size_t)kNP * 512;  // [NP,512] wb-KM
  float* tr_a = (float*)R;                  // fp32 view, disjoint lifetime
  float* tr_p = tr_a + (size_t)kNA * 256;
  char* afterR = (char*)(km_wbp + (size_t)kNP * 512);
  bf16* agg_a = (bf16*)afterR;
  bf16* agg_p = agg_a + (size_t)kNA * 256;

  const bf16* c_ew_wb = canon + kOff(0);
  const bf16* c_ew_w  = canon + kOff(1);
  const bf16* c_ew_c  = canon + kOff(2);
  const bf16* c_adW   = canon + kOff(3);
  const bf16* c_adb   = canon + kOff(4);
  const bf16* c_kW    = canon + kOff(5);
  const bf16* c_kb    = canon + kOff(6);
  const bf16* c_qW    = canon + kOff(7);
  const bf16* c_qb    = canon + kOff(8);
  const bf16* c_mW    = canon + kOff(9);
  const bf16* c_mb    = canon + kOff(10);
  const bf16* c_aW    = canon + kOff(11);
  const bf16* c_ab    = canon + kOff(12);
  const bf16* c_wpri  = canon + kOff(13);
  const bf16* c_watt  = canon + kOff(14);
  const bf16* c_wmsg  = canon + kOff(15);
  const bf16* c_skip  = canon + kOff(16);
  const bf16* c_lng   = canon + kOff(17);
  const bf16* c_lnb   = canon + kOff(18);
  const bf16* c_outW  = canon + kOff(19);
  const bf16* c_outb  = canon + kOff(20);

  const unsigned* fIn = flags + 0;
  const unsigned* f1  = flags + 1;

  detect_dtype<<<1, 256, 0, stream>>>((const unsigned*)d_in[0], flags);

  CanonArgs ca;
  for (int s = 0; s < kNSeg; ++s) { ca.n[s] = kSegN[s]; ca.dstOff[s] = (unsigned)kOff(s); }
  const int srcIdx[kNSeg] = {2,3,4, 5,6, 7,8, 9,10, 11,12, 13,14, 15, 16,17, 18,19,20, 21,22};
  for (int s = 0; s < kNSeg; ++s) ca.src[s] = d_in[srcIdx[s]];
  canon_kernel<<<dim3(1172, kNSeg), 256, 0, stream>>>(ca, canon, flags);

  TransArgs ta;
  ta.src[0] = c_adW;              ta.dst[0] = adWT;
  ta.src[1] = c_adW + 65536;      ta.dst[1] = adWT + 65536;
  for (int m = 0; m < 4; ++m) { ta.src[2 + m] = c_qW + (size_t)m * 65536; ta.dst[2 + m] = qWT + (size_t)m * 65536; }
  for (int m = 0; m < 4; ++m) { ta.src[6 + m] = c_aW + (size_t)m * 65536; ta.dst[6 + m] = aWT + (size_t)m * 65536; }
  transpose_w<<<dim3(4, 4, 10), 256, 0, stream>>>(ta);

  // ---- CSR build ----
  hipMemsetAsync(cur_wb, 0, (size_t)((kNA + 1) + 2 * (kNP + 1)) * 4, stream);
  HistArgs ha;
  ha.dst[0] = dst_wb; ha.cnt[0] = cur_wb; ha.E[0] = kEWB;
  ha.dst[1] = dst_w;  ha.cnt[1] = cur_w;  ha.E[1] = kEW;
  ha.dst[2] = dst_c;  ha.cnt[2] = cur_c;  ha.E[2] = kEC;
  csr_hist<<<dim3((kEC + 255) / 256, 3), 256, 0, stream>>>(ha);
  ScanArgs sa;
  sa.deg[0] = cur_wb;  sa.offs[0] = offs_wb; sa.N[0] = kNA;
  sa.deg[1] = cur_w;   sa.offs[1] = offs_w;  sa.N[1] = kNP;
  sa.deg[2] = cur_c;   sa.offs[2] = offs_c;  sa.N[2] = kNP;
  sa.bsums = bsums;
  scan_l1<<<dim3(32, 3), 256, 0, stream>>>(sa);
  scan_l2<<<3, 64, 0, stream>>>(bsums, totals);
  scan_l3<<<dim3(20, 3), 256, 0, stream>>>(sa, totals);
  ScatArgs sc;
  sc.dst[0] = dst_wb; sc.src[0] = src_wb; sc.ew[0] = c_ew_wb; sc.cur[0] = cur_wb;
  sc.srcs[0] = srcs_wb; sc.ews[0] = ews_wb; sc.E[0] = kEWB;
  sc.dst[1] = dst_w;  sc.src[1] = src_w;  sc.ew[1] = c_ew_w;  sc.cur[1] = cur_w;
  sc.srcs[1] = srcs_w;  sc.ews[1] = ews_w;  sc.E[1] = kEW;
  sc.dst[2] = dst_c;  sc.src[2] = src_c;  sc.ew[2] = c_ew_c;  sc.cur[2] = cur_c;
  sc.srcs[2] = srcs_c;  sc.ews[2] = ews_c;  sc.E[2] = kEC;
  csr_scatter<<<dim3((kEC + 255) / 256, 3), 256, 0, stream>>>(sc);

  combine_weights<<<dim3(8, 24), 256, 0, stream>>>(c_kW, c_kb, c_watt, KMeffT, kmbeT, 0);
  combine_weights<<<dim3(8, 24), 256, 0, stream>>>(c_mW, c_mb, c_wmsg, KMeffT, kmbeT, 256);

  const int ntA = (kNA + 127) / 128;   // 157
  const int ntP = (kNP + 127) / 128;   // 313
  auto sgrid = [](int maxnt, int nslab) {
    return dim3((unsigned)(((maxnt + 7) / 8) * 8 * nslab));
  };
  auto mkd = [](const bf16* wt, const bf16* bias, const void* A, void* c,
                int ldc, int coff, int act, int otype, int M, int ntiles) {
    GemmDesc g;
    g.wt = (const short*)wt; g.bias = bias; g.A = A; g.c = c; g.ldc = ldc;
    g.coff = coff; g.act = act; g.otype = otype; g.M = M; g.ntiles = ntiles;
    return g;
  };

  // adapt: SPLIT dispatches (r12 fused version regressed to 182 us)
  {
    MultiDesc md{};
    md.d[0] = mkd(adWT,             c_adb,       d_in[0], fa, 256, 0,   1, 0, kNA, ntA);
    md.d[1] = mkd(adWT + 128 * 256, c_adb + 128, d_in[0], fa, 256, 128, 1, 0, kNA, ntA);
    mfma_gemm128<<<sgrid(ntA, 2), 256, 0, stream>>>(fIn, md, 2);
    md.d[0] = mkd(adWT + 65536,             c_adb + 256, d_in[1], fp_, 256, 0,   1, 0, kNP, ntP);
    md.d[1] = mkd(adWT + 65536 + 128 * 256, c_adb + 384, d_in[1], fp_, 256, 128, 1, 0, kNP, ntP);
    mfma_gemm128<<<sgrid(ntP, 2), 256, 0, stream>>>(fIn, md, 2);
  }

  for (int l = 0; l < 2; ++l) {
    const bf16* qW_a = qWT + (size_t)(l * 2 + 0) * 65536;
    const bf16* qW_p = qWT + (size_t)(l * 2 + 1) * 65536;
    const bf16* qb_a = c_qb + (l * 2 + 0) * 256;
    const bf16* qb_p = c_qb + (l * 2 + 1) * 256;
    const bf16* KM_c  = KMeffT + (size_t)(l * 3 + 0) * 512 * 256;
    const bf16* KM_w  = KMeffT + (size_t)(l * 3 + 1) * 512 * 256;
    const bf16* KM_wb = KMeffT + (size_t)(l * 3 + 2) * 512 * 256;
    const bf16* kb_c  = kmbeT + (l * 3 + 0) * 512;
    const bf16* kb_w  = kmbeT + (l * 3 + 1) * 512;
    const bf16* kb_wb = kmbeT + (l * 3 + 2) * 512;

    // (1) mega-GEMM: all projections for this layer in ONE dispatch
    {
      MultiDesc md{};
      md.d[0] = mkd(qW_p,             qb_p,       fp_, qp, 256, 0,   0, 0, kNP, ntP);
      md.d[1] = mkd(qW_p + 128 * 256, qb_p + 128, fp_, qp, 256, 128, 0, 0, kNP, ntP);
      for (int s = 0; s < 4; ++s)
        md.d[2 + s] = mkd(KM_c + (size_t)s * 128 * 256, kb_c + s * 128, fp_, km_cp, 512, s * 128, 0, 0, kNP, ntP);
      md.d[6] = mkd(qW_a,             qb_a,       fa, qa, 256, 0,   0, 0, kNA, ntA);
      md.d[7] = mkd(qW_a + 128 * 256, qb_a + 128, fa, qa, 256, 128, 0, 0, kNA, ntA);
      for (int s = 0; s < 4; ++s)
        md.d[8 + s] = mkd(KM_w + (size_t)s * 128 * 256, kb_w + s * 128, fa, km_a, 512, s * 128, 0, 0, kNA, ntA);
      for (int s = 0; s < 4; ++s)
        md.d[12 + s] = mkd(KM_wb + (size_t)s * 128 * 256, kb_wb + s * 128, fp_, km_wbp, 512, s * 128, 0, 0, kNP, ntP);
      mfma_gemm128<<<sgrid(ntP, 16), 256, 0, stream>>>(f1, md, 16);
    }
    // (2) tri-gather: authors (wb) + papers (cites + writes), one dispatch
    {
      TriDesc td;
      td.qa = qa; td.qp = qp;
      td.km_wb = km_wbp; td.km_c = km_cp; td.km_w = km_a;
      td.srcs_wb = srcs_wb; td.srcs_c = srcs_c; td.srcs_w = srcs_w;
      td.ews_wb = ews_wb; td.ews_c = ews_c; td.ews_w = ews_w;
      td.offs_wb = offs_wb; td.offs_c = offs_c; td.offs_w = offs_w;
      td.pri_wb = c_wpri + (l * 3 + 2) * 4;
      td.pri_c  = c_wpri + (l * 3 + 0) * 4;
      td.pri_w  = c_wpri + (l * 3 + 1) * 4;
      td.agg_a = agg_a; td.agg_p = agg_p;
      const int bA = (kNA + 3) / 4;
      tri_gather<<<bA + (kNP + 3) / 4, 256, 0, stream>>>(td, bA);
    }
    // (3) fused A-projection (authors + papers) -> fp32 tr (aliases q/km)
    {
      const bf16* aW_a = aWT + (size_t)(l * 2 + 0) * 65536;
      const bf16* aW_p = aWT + (size_t)(l * 2 + 1) * 65536;
      MultiDesc md{};
      md.d[0] = mkd(aW_a,             c_ab + (l * 2 + 0) * 256,       agg_a, tr_a, 256, 0,   0, 1, kNA, ntA);
      md.d[1] = mkd(aW_a + 128 * 256, c_ab + (l * 2 + 0) * 256 + 128, agg_a, tr_a, 256, 128, 0, 1, kNA, ntA);
      md.d[2] = mkd(aW_p,             c_ab + (l * 2 + 1) * 256,       agg_p, tr_p, 256, 0,   0, 1, kNP, ntP);
      md.d[3] = mkd(aW_p + 128 * 256, c_ab + (l * 2 + 1) * 256 + 128, agg_p, tr_p, 256, 128, 0, 1, kNP, ntP);
      mfma_gemm128<<<sgrid(ntP, 4), 256, 0, stream>>>(f1, md, 4);
    }
    // (4) fused skip+LN
    skip_ln2<<<(kNA + kNP) / 4, 256, 0, stream>>>(
        tr_a, fa,  c_skip + l * 3 + 0, c_lng + (l * 2 + 0) * 256, c_lnb + (l * 2 + 0) * 256,
        tr_p, fp_, c_skip + l * 3 + 1, c_lng + (l * 2 + 1) * 256, c_lnb + (l * 2 + 1) * 256,
        kNA, kNA + kNP);
  }

  out_gemm<<<kNP / 64, 256, 0, stream>>>(fp_, c_outW, c_outb, d_out, fIn, kNP);
}

// Round 14
// 819.246 us; speedup vs baseline: 1.2711x; 1.0048x over previous
//
#include <hip/hip_runtime.h>
#include <hip/hip_bf16.h>
#include <math.h>

using bf16 = __hip_bfloat16;

typedef __attribute__((ext_vector_type(8))) short short8;   // 8 bf16 (4 VGPRs)
typedef __attribute__((ext_vector_type(4))) float float4v;  // MFMA acc

static constexpr int kNA  = 20000;
static constexpr int kNP  = 40000;
static constexpr int kEWB = 150000;
static constexpr int kEW  = 150000;
static constexpr int kEC  = 300000;

// ---- canonical bf16 input region ----
static constexpr int kNSeg = 21;
static constexpr int kSegN[kNSeg] = {
  150000, 150000, 300000,           // ew_wb, ew_w, ew_c
  131072, 512,                      // adW, adb
  262144, 1024,                     // kW, kb
  262144, 1024,                     // qW, qb
  262144, 1024,                     // mW, mb
  262144, 1024,                     // aW, ab
  24,                               // wpri
  98304, 98304,                     // watt, wmsg
  6, 1024, 1024,                    // skip, lng, lnb
  16384, 64                         // outW, outb
};
static constexpr size_t kOff(int s) {
  size_t o = 0;
  for (int i = 0; i < s; ++i) o += (size_t)kSegN[i];
  return o;
}
static constexpr size_t kCanonTotal = kOff(kNSeg);

struct CanonArgs {
  const void* src[kNSeg];
  int n[kNSeg];
  unsigned dstOff[kNSeg];
};
struct TransArgs {
  const bf16* src[10];
  bf16* dst[10];
};
// per-slab GEMM descriptor (slab = 128 output cols); per-slab A/M/ntiles
struct GemmDesc {
  const short* wt;   // [128][256] n-major slab
  const bf16* bias;  // 128 entries (slab-local)
  const void* A;     // input activations
  void* c;           // output base
  int ldc;
  int coff;
  int act;           // 1 = gelu
  int otype;         // 0 = bf16, 1 = fp32
  int M;
  int ntiles;        // ceil(M/128)
};
struct MultiDesc { GemmDesc d[16]; };
// three-relation scan / hist / scatter descriptors
struct ScanArgs {
  int* deg[3];
  int* offs[3];
  int* bsums;
  int N[3];
};
struct HistArgs {
  const int* dst[3];
  int* cnt[3];
  int E[3];
};
struct ScatArgs {
  const int* dst[3];
  const int* src[3];
  const bf16* ew[3];
  int* cur[3];
  int* srcs[3];
  bf16* ews[3];
  int E[3];
};
// tri-relation gather descriptor (authors: wb; papers: cites + writes)
struct TriDesc {
  const bf16* qa; const bf16* qp;
  const bf16* km_wb;  // [NP,512]
  const bf16* km_c;   // [NP,512]
  const bf16* km_w;   // [NA,512]
  const int* srcs_wb; const int* srcs_c; const int* srcs_w;
  const bf16* ews_wb; const bf16* ews_c; const bf16* ews_w;
  const int* offs_wb; const int* offs_c; const int* offs_w;
  const bf16* pri_wb; const bf16* pri_c; const bf16* pri_w;
  bf16* agg_a; bf16* agg_p;
};

__device__ __forceinline__ float toF(float x) { return x; }
__device__ __forceinline__ float toF(bf16 x)  { return __bfloat162float(x); }
__device__ __forceinline__ float bits2f(unsigned short b) {
  unsigned int u = ((unsigned int)b) << 16;
  return __uint_as_float(u);
}
__device__ __forceinline__ float sigmoidf_(float x) { return 1.0f / (1.0f + expf(-x)); }
__device__ __forceinline__ float gelu_exact(float x) {
  return 0.5f * x * (1.0f + erff(x * 0.70710678118654752f));
}

// -------------------------------------------------------------------------
__global__ __launch_bounds__(256) void detect_dtype(
    const unsigned* __restrict__ x, unsigned* __restrict__ flags)
{
  __shared__ int cnt;
  if (threadIdx.x == 0) cnt = 0;
  __syncthreads();
  unsigned w = x[threadIdx.x];
  unsigned e = (w >> 7) & 0xFFu;
  if (e >= 110u && e <= 140u) atomicAdd(&cnt, 1);
  __syncthreads();
  if (threadIdx.x == 0) {
    flags[0] = (cnt >= 128) ? 1u : 0u;
    flags[1] = 1u;
  }
}

__global__ __launch_bounds__(256) void canon_kernel(
    CanonArgs a, bf16* __restrict__ dst, const unsigned* __restrict__ flags)
{
  const int s = blockIdx.y;
  const int i = blockIdx.x * 256 + threadIdx.x;
  if (i >= a.n[s]) return;
  bf16 v;
  if (flags[0]) v = ((const bf16*)a.src[s])[i];
  else          v = __float2bfloat16(((const float*)a.src[s])[i]);
  dst[a.dstOff[s] + i] = v;
}

// -------------------------------------------------------------------------
__global__ __launch_bounds__(256) void transpose_w(TransArgs ta)
{
  const int m = blockIdx.z;
  const short* src = (const short*)ta.src[m];
  short* dst = (short*)ta.dst[m];
  const int k0 = blockIdx.x * 64, n0 = blockIdx.y * 64;
  __shared__ short tile[64][65];
  const int tx = threadIdx.x & 63, ty = threadIdx.x >> 6;
  for (int i = ty; i < 64; i += 4)
    tile[i][tx] = src[(size_t)(k0 + i) * 256 + n0 + tx];
  __syncthreads();
  for (int i = ty; i < 64; i += 4)
    dst[(size_t)(n0 + i) * 256 + k0 + tx] = tile[tx][i];
}

// -------------------------------------------------------------------------
// CSR build: fused histogram -> 3-level parallel scan -> fused scatter.
// -------------------------------------------------------------------------
__global__ __launch_bounds__(256) void csr_hist(HistArgs h)
{
  const int rel = blockIdx.y;
  const int i = blockIdx.x * 256 + threadIdx.x;
  if (i < h.E[rel]) atomicAdd(&h.cnt[rel][h.dst[rel][i]], 1);
}

__global__ __launch_bounds__(256) void scan_l1(ScanArgs a)
{
  const int rel = blockIdx.y;
  const int N = a.N[rel];
  const int t = threadIdx.x;
  const int lane = t & 63;
  const int wid = t >> 6;
  const int i0 = blockIdx.x * 2048 + t * 8;
  const int* deg = a.deg[rel];
  int v[8];
  int T = 0;
  #pragma unroll
  for (int j = 0; j < 8; ++j) {
    v[j] = (i0 + j < N) ? deg[i0 + j] : 0;
    T += v[j];
  }
  int incl = T;
  #pragma unroll
  for (int off = 1; off < 64; off <<= 1) {
    const int u = __shfl_up(incl, off);
    if (lane >= off) incl += u;
  }
  __shared__ int wsum[4];
  if (lane == 63) wsum[wid] = incl;
  __syncthreads();
  int woff = 0;
  #pragma unroll
  for (int wp = 0; wp < 4; ++wp) if (wp < wid) woff += wsum[wp];
  int run = woff + incl - T;
  int* offs = a.offs[rel];
  #pragma unroll
  for (int j = 0; j < 8; ++j) {
    if (i0 + j < N) offs[i0 + j] = run;
    run += v[j];
  }
  if (t == 0)
    a.bsums[rel * 32 + blockIdx.x] = wsum[0] + wsum[1] + wsum[2] + wsum[3];
}

__global__ __launch_bounds__(64) void scan_l2(int* __restrict__ bsums,
                                              int* __restrict__ totals)
{
  const int rel = blockIdx.x;
  const int lane = threadIdx.x;
  const int v = (lane < 32) ? bsums[rel * 32 + lane] : 0;
  int incl = v;
  #pragma unroll
  for (int off = 1; off < 64; off <<= 1) {
    const int u = __shfl_up(incl, off);
    if (lane >= off) incl += u;
  }
  if (lane < 32) bsums[rel * 32 + lane] = incl - v;
  if (lane == 63) totals[rel] = incl;
}

__global__ __launch_bounds__(256) void scan_l3(ScanArgs a,
                                               const int* __restrict__ totals)
{
  const int rel = blockIdx.y;
  const int N = a.N[rel];
  const int i0 = blockIdx.x * 2048 + threadIdx.x * 8;
  const int boff = a.bsums[rel * 32 + blockIdx.x];
  int* offs = a.offs[rel];
  int* cur = a.deg[rel];
  #pragma unroll
  for (int j = 0; j < 8; ++j) {
    const int idx = i0 + j;
    if (idx < N) {
      const int o = offs[idx] + boff;
      offs[idx] = o;
      cur[idx] = o;
    }
  }
  if (blockIdx.x == 0 && threadIdx.x == 0) offs[N] = totals[rel];
}

__global__ __launch_bounds__(256) void csr_scatter(ScatArgs s)
{
  const int rel = blockIdx.y;
  const int i = blockIdx.x * 256 + threadIdx.x;
  if (i >= s.E[rel]) return;
  const int p = atomicAdd(&s.cur[rel][s.dst[rel][i]], 1);
  s.srcs[rel][p] = s.src[rel][i];
  s.ews[rel][p]  = s.ew[rel][i];
}

// -------------------------------------------------------------------------
// Fold per-head w_att/w_msg into K/M projections; emit fused-transposed
// KMT[l,e][512][256] bf16 + bias kmb[l,e][512]. grid (8, 24).
// -------------------------------------------------------------------------
__global__ __launch_bounds__(256) void combine_weights(
    const bf16* __restrict__ Wbig, const bf16* __restrict__ bbig,
    const bf16* __restrict__ wsm, bf16* __restrict__ KMT,
    bf16* __restrict__ kmb, int noff)
{
  const int blk = blockIdx.y;
  const int rc  = blockIdx.x;
  const int h = blk & 3;
  const int le = blk >> 2;
  const int e = le % 3;
  const int l = le / 3;
  const int st = (e == 1) ? 0 : 1;

  const short* Wsrc = (const short*)(Wbig + (size_t)(l * 2 + st) * 65536);
  const bf16*  bsrc = bbig + (size_t)(l * 2 + st) * 256;
  const short* wm   = (const short*)(wsm + ((size_t)(l * 3 + e) * 4 + h) * 4096);
  short* outT = (short*)(KMT + (size_t)(l * 3 + e) * 512 * 256);
  bf16* outb  = kmb + (size_t)(l * 3 + e) * 512;

  __shared__ short w[64][72];
  __shared__ short As[32][72];
  __shared__ short ot[64][40];

  const int t = threadIdx.x;
  {
    const int base = t * 16;
    const int r0 = base >> 6, c0 = base & 63;
    *(short8*)&w[r0][c0]     = *(const short8*)&wm[base];
    *(short8*)&w[r0][c0 + 8] = *(const short8*)&wm[base + 8];
  }
  {
    const int row = t >> 3;
    const int kc = (t & 7) * 8;
    *(short8*)&As[row][kc] =
        *(const short8*)&Wsrc[(size_t)(rc * 32 + row) * 256 + h * 64 + kc];
  }
  __syncthreads();

  const int j   = t & 63;
  const int sub = t >> 6;
  float accv[8] = {};
  #pragma unroll
  for (int d = 0; d < 64; ++d) {
    const float wd = bits2f((unsigned short)w[d][j]);
    #pragma unroll
    for (int r8 = 0; r8 < 8; ++r8)
      accv[r8] += bits2f((unsigned short)As[sub * 8 + r8][d]) * wd;
  }
  #pragma unroll
  for (int r8 = 0; r8 < 8; ++r8) {
    union { bf16 h; short s; } cv;
    cv.h = __float2bfloat16(accv[r8]);
    ot[j][sub * 8 + r8] = cv.s;
  }

  if (rc == 0 && t < 64) {
    float acc = 0.f;
    #pragma unroll
    for (int d = 0; d < 64; ++d)
      acc += toF(bsrc[h * 64 + d]) * bits2f((unsigned short)w[d][t]);
    outb[h * 64 + t + noff] = __float2bfloat16(acc);
  }
  __syncthreads();
  {
    const int nn = t >> 2;
    const int kx = (t & 3) * 8;
    short8 v;
    #pragma unroll
    for (int x = 0; x < 8; ++x) v[x] = ot[nn][kx + x];
    *(short8*)&outT[(size_t)(h * 64 + nn + noff) * 256 + rc * 32 + kx] = v;
  }
}

// -------------------------------------------------------------------------
// Multi-output MFMA GEMM with per-slab A/M/ntiles. Tile 128x128, BK=64,
// 4 waves in 2x2. XCD swizzle [r11: FETCH 63->21.7 MB]. bf16 epilogue is
// LDS-staged for full-sector 16B/lane stores (r13 showed 1.65x write
// amplification from scattered 2-byte stores).
// -------------------------------------------------------------------------
__global__ __launch_bounds__(256, 4) void mfma_gemm128(
    const unsigned* __restrict__ aflag, MultiDesc md, int nslab)
{
  __shared__ short As[128][72];
  __shared__ short Bs[128][72];
  const int lid = blockIdx.x;
  const int grp = lid / (8 * nslab);
  const int rem = lid - grp * 8 * nslab;
  const int slab = rem >> 3;
  const int tx = grp * 8 + (rem & 7);
  const GemmDesc d = md.d[slab];
  if (tx >= d.ntiles) return;
  const bool abf = (*aflag != 0u);
  const int M = d.M;
  const int t = threadIdx.x;
  const int bm = tx * 128;
  const int lane = t & 63;
  const int wid  = t >> 6;
  const int wm = (wid >> 1) * 64;
  const int wn = (wid & 1) * 64;
  const int col16 = lane & 15;
  const int quad  = lane >> 4;
  const int rr = t >> 3;
  const int kk = (t & 7) * 8;

  float4v acc[4][4];
  #pragma unroll
  for (int mi = 0; mi < 4; ++mi)
    #pragma unroll
    for (int ni = 0; ni < 4; ++ni) acc[mi][ni] = (float4v){0.f, 0.f, 0.f, 0.f};

  for (int k0 = 0; k0 < 256; k0 += 64) {
    #pragma unroll
    for (int it = 0; it < 4; ++it) {
      const int row = it * 32 + rr;
      const int grow = bm + row;
      short8 v = (short8){0, 0, 0, 0, 0, 0, 0, 0};
      if (grow < M) {
        if (abf) {
          v = *(const short8*)((const short*)d.A + (size_t)grow * 256 + k0 + kk);
        } else {
          const float* ap = (const float*)d.A + (size_t)grow * 256 + k0 + kk;
          #pragma unroll
          for (int j = 0; j < 8; ++j) {
            union { bf16 h; short s; } cv;
            cv.h = __float2bfloat16(ap[j]);
            v[j] = cv.s;
          }
        }
      }
      *(short8*)&As[row][kk] = v;
    }
    #pragma unroll
    for (int it = 0; it < 4; ++it) {
      const int n = it * 32 + rr;
      *(short8*)&Bs[n][kk] = *(const short8*)&d.wt[(size_t)n * 256 + k0 + kk];
    }
    __syncthreads();

    #pragma unroll
    for (int ks = 0; ks < 64; ks += 32) {
      short8 bfr[4];
      #pragma unroll
      for (int ni = 0; ni < 4; ++ni)
        bfr[ni] = *(const short8*)&Bs[wn + ni * 16 + col16][ks + quad * 8];
      #pragma unroll
      for (int mi = 0; mi < 4; ++mi) {
        const short8 afr = *(const short8*)&As[wm + mi * 16 + col16][ks + quad * 8];
        #pragma unroll
        for (int ni = 0; ni < 4; ++ni)
          acc[mi][ni] = __builtin_amdgcn_mfma_f32_16x16x32_bf16(afr, bfr[ni], acc[mi][ni], 0, 0, 0);
      }
    }
    __syncthreads();
  }

  if (d.otype == 0) {
    // --- coalesced bf16 epilogue: stage column-half in LDS, 16B stores ---
    #pragma unroll
    for (int p = 0; p < 2; ++p) {
      if ((wid & 1) == p) {
        #pragma unroll
        for (int ni = 0; ni < 4; ++ni) {
          const int lcol = ni * 16 + col16;        // 0..63 within half
          const float bc = toF(d.bias[p * 64 + lcol]);
          #pragma unroll
          for (int mi = 0; mi < 4; ++mi) {
            #pragma unroll
            for (int r = 0; r < 4; ++r) {
              float v = acc[mi][ni][r] + bc;
              if (d.act == 1) v = gelu_exact(v);
              union { bf16 h; short s; } cv;
              cv.h = __float2bfloat16(v);
              As[wm + mi * 16 + quad * 4 + r][lcol] = cv.s;
            }
          }
        }
      }
      __syncthreads();
      #pragma unroll
      for (int j = 0; j < 4; ++j) {
        const int f = j * 256 + t;
        const int row = f >> 3;     // 0..127
        const int u = f & 7;        // uint4 index within 64-col half
        if (bm + row < M) {
          *(short8*)((short*)d.c + (size_t)(bm + row) * d.ldc + d.coff + p * 64 + u * 8) =
              *(const short8*)&As[row][u * 8];
        }
      }
      __syncthreads();
    }
  } else {
    // fp32 output: 16-lane runs are already 64B sectors
    #pragma unroll
    for (int ni = 0; ni < 4; ++ni) {
      const int col = wn + ni * 16 + col16;
      const float bc = toF(d.bias[col]);
      const int gcol = d.coff + col;
      #pragma unroll
      for (int mi = 0; mi < 4; ++mi) {
        #pragma unroll
        for (int r = 0; r < 4; ++r) {
          const int row = bm + wm + mi * 16 + quad * 4 + r;
          if (row < M) {
            float v = acc[mi][ni][r] + bc;
            if (d.act == 1) v = gelu_exact(v);
            ((float*)d.c)[(size_t)row * d.ldc + gcol] = v;
          }
        }
      }
    }
  }
}

// -------------------------------------------------------------------------
// Tri-relation gather: author blocks do WB -> agg_a; paper blocks do
// CITES + WRITES accumulated in registers in ONE pass -> agg_p.
// -------------------------------------------------------------------------
__device__ __forceinline__ void gather_loop(
    const float qf[8], const bf16* km, const int* srcs, const bf16* ews,
    int beg, int end, int h, int sl, float prih, float acc[8])
{
  union B8 { uint4 u; unsigned short s[8]; };
  for (int idx = beg + h; idx < end; idx += 2) {
    const int s = srcs[idx];
    const float w = toF(ews[idx]);
    B8 kb;
    kb.u = ((const uint4*)(km + (size_t)s * 512))[sl];
    float dot = 0.f;
    #pragma unroll
    for (int j = 0; j < 8; ++j) dot += qf[j] * bits2f(kb.s[j]);
    dot += __shfl_xor(dot, 1);
    dot += __shfl_xor(dot, 2);
    dot += __shfl_xor(dot, 4);
    const float a = w * sigmoidf_(dot * prih * 0.125f);
    B8 mb;
    mb.u = ((const uint4*)(km + (size_t)s * 512 + 256))[sl];
    #pragma unroll
    for (int j = 0; j < 8; ++j) acc[j] += bits2f(mb.s[j]) * a;
  }
}

__global__ __launch_bounds__(256) void tri_gather(TriDesc td, int bA)
{
  const bool isA = (blockIdx.x < (unsigned)bA);
  const int bidx = isA ? blockIdx.x : blockIdx.x - bA;
  const int lane = threadIdx.x & 63;
  const int wid  = threadIdx.x >> 6;
  const int node = bidx * 4 + wid;
  const int Nd = isA ? kNA : kNP;
  if (node >= Nd) return;
  const int h  = lane >> 5;
  const int sl = lane & 31;

  union B8 { uint4 u; unsigned short s[8]; };
  const bf16* q = isA ? td.qa : td.qp;
  B8 qv;
  qv.u = ((const uint4*)(q + (size_t)node * 256))[sl];
  float qf[8];
  #pragma unroll
  for (int j = 0; j < 8; ++j) qf[j] = bits2f(qv.s[j]);

  float acc[8] = {};
  float scale;
  bf16* aggout;
  if (isA) {
    gather_loop(qf, td.km_wb, td.srcs_wb, td.ews_wb,
                td.offs_wb[node], td.offs_wb[node + 1], h, sl,
                toF(td.pri_wb[sl >> 3]), acc);
    scale = 1.f;
    aggout = td.agg_a;
  } else {
    gather_loop(qf, td.km_c, td.srcs_c, td.ews_c,
                td.offs_c[node], td.offs_c[node + 1], h, sl,
                toF(td.pri_c[sl >> 3]), acc);
    gather_loop(qf, td.km_w, td.srcs_w, td.ews_w,
                td.offs_w[node], td.offs_w[node + 1], h, sl,
                toF(td.pri_w[sl >> 3]), acc);
    scale = 0.5f;
    aggout = td.agg_p;
  }

  #pragma unroll
  for (int j = 0; j < 8; ++j) acc[j] += __shfl_xor(acc[j], 32);

  if (h == 0) {
    B8 ov;
    #pragma unroll
    for (int j = 0; j < 8; ++j) {
      union { bf16 h; unsigned short u; } cv;
      cv.h = __float2bfloat16(acc[j] * scale);
      ov.s[j] = cv.u;
    }
    *(uint4*)(aggout + (size_t)node * 256 + sl * 8) = ov.u;
  }
}

// -------------------------------------------------------------------------
// Fused skip+LN over both node types: node-range decode. One wave per node.
// -------------------------------------------------------------------------
__global__ __launch_bounds__(256) void skip_ln2(
    const float* __restrict__ trA, bf16* __restrict__ featA,
    const bf16* __restrict__ skA, const bf16* __restrict__ gA_, const bf16* __restrict__ bA,
    const float* __restrict__ trP, bf16* __restrict__ featP,
    const bf16* __restrict__ skP, const bf16* __restrict__ gP, const bf16* __restrict__ bP,
    int NA, int Ntot)
{
  const int lane = threadIdx.x & 63;
  const int wid  = threadIdx.x >> 6;
  int node = blockIdx.x * 4 + wid;
  if (node >= Ntot) return;
  const float* tr; bf16* feat; const bf16 *sk, *g, *b;
  if (node < NA) { tr = trA; feat = featA; sk = skA; g = gA_; b = bA; }
  else { node -= NA; tr = trP; feat = featP; sk = skP; g = gP; b = bP; }

  const float alpha = sigmoidf_(toF(*sk));
  const float4 t = ((const float4*)(tr + (size_t)node * 256))[lane];
  union B4 { uint2 u; unsigned short s[4]; };
  B4 fb;
  fb.u = ((const uint2*)(feat + (size_t)node * 256))[lane];
  float o[4];
  o[0] = t.x * alpha + bits2f(fb.s[0]) * (1.f - alpha);
  o[1] = t.y * alpha + bits2f(fb.s[1]) * (1.f - alpha);
  o[2] = t.z * alpha + bits2f(fb.s[2]) * (1.f - alpha);
  o[3] = t.w * alpha + bits2f(fb.s[3]) * (1.f - alpha);

  float sum = o[0] + o[1] + o[2] + o[3];
  #pragma unroll
  for (int off = 32; off; off >>= 1) sum += __shfl_xor(sum, off);
  const float mu = sum * (1.f / 256.f);

  float dd[4], sq = 0.f;
  #pragma unroll
  for (int j = 0; j < 4; ++j) { dd[j] = o[j] - mu; sq += dd[j] * dd[j]; }
  #pragma unroll
  for (int off = 32; off; off >>= 1) sq += __shfl_xor(sq, off);
  const float rs = rsqrtf(sq * (1.f / 256.f) + 1e-5f);

  bf16* fout = feat + (size_t)node * 256 + lane * 4;
  #pragma unroll
  for (int j = 0; j < 4; ++j) {
    float r = dd[j] * rs * toF(g[lane * 4 + j]) + toF(b[lane * 4 + j]);
    fout[j] = __float2bfloat16(r);
  }
}

// -------------------------------------------------------------------------
// out[M,64] = A[M,256] @ W[256,64] + b[64]; output dtype per *flag.
// -------------------------------------------------------------------------
__global__ __launch_bounds__(256) void out_gemm(
    const bf16* __restrict__ A, const bf16* __restrict__ W,
    const bf16* __restrict__ bias, void* __restrict__ out,
    const unsigned* __restrict__ flag, int M)
{
  __shared__ float Ws[64][64];
  const bool obf = (*flag != 0u);
  const int tid = threadIdx.x;
  const int row = blockIdx.x * 64 + (tid >> 2);
  const int c0 = (tid & 3) * 16;
  const int arow = (row < M) ? row : 0;
  const bf16* a = A + (size_t)arow * 256;
  float acc[16] = {};
  for (int k0 = 0; k0 < 256; k0 += 64) {
    for (int i = tid; i < 4096; i += 256)
      Ws[i >> 6][i & 63] = toF(W[(size_t)(k0 + (i >> 6)) * 64 + (i & 63)]);
    __syncthreads();
    for (int k = 0; k < 64; ++k) {
      const float av = toF(a[k0 + k]);
      #pragma unroll
      for (int j = 0; j < 16; ++j) acc[j] += av * Ws[k][c0 + j];
    }
    __syncthreads();
  }
  if (row < M) {
    #pragma unroll
    for (int j = 0; j < 16; ++j) {
      const float v = acc[j] + toF(bias[c0 + j]);
      const size_t idx = (size_t)row * 64 + c0 + j;
      if (obf) ((bf16*)out)[idx] = __float2bfloat16(v);
      else     ((float*)out)[idx] = v;
    }
  }
}

// -------------------------------------------------------------------------
extern "C" void kernel_launch(void* const* d_in, const int* in_sizes, int n_in,
                              void* d_out, int out_size, void* d_ws, size_t ws_size,
                              hipStream_t stream) {
  const int* src_wb  = (const int*)d_in[23];
  const int* dst_wb  = (const int*)d_in[24];
  const int* src_w   = (const int*)d_in[25];
  const int* dst_w   = (const int*)d_in[26];
  const int* src_c   = (const int*)d_in[27];
  const int* dst_c   = (const int*)d_in[28];

  // ---- workspace carve (~204 MB total) ----
  char* base = (char*)d_ws;
  unsigned* flags = (unsigned*)base;
  bf16* canon = (bf16*)(base + 256);
  char* p = base + 256 + (((size_t)kCanonTotal * 2 + 511) & ~(size_t)511);
  bf16* adWT = (bf16*)p;
  bf16* qWT  = adWT + (size_t)2 * 65536;
  bf16* aWT  = qWT  + (size_t)4 * 65536;
  bf16* KMeffT = aWT + (size_t)4 * 65536;    // 6 x 512*256
  bf16* kmbeT  = KMeffT + (size_t)6 * 512 * 256;
  char* pc = (char*)(((size_t)(kmbeT + 6 * 512) + 511) & ~(size_t)511);
  int* cur_wb  = (int*)pc;
  int* cur_w   = cur_wb + (kNA + 1);
  int* cur_c   = cur_w + (kNP + 1);
  int* offs_wb = cur_c + (kNP + 1);
  int* offs_w  = offs_wb + (kNA + 1);
  int* offs_c  = offs_w + (kNP + 1);
  int* srcs_wb = offs_c + (kNP + 1);
  int* srcs_w  = srcs_wb + kEWB;
  int* srcs_c  = srcs_w + kEW;
  bf16* ews_wb = (bf16*)(srcs_c + kEC);
  bf16* ews_w  = ews_wb + kEWB;
  bf16* ews_c  = ews_w + kEW;
  int* bsums   = (int*)(ews_c + kEC);
  int* totals  = bsums + 96;
  char* p2 = (char*)(((size_t)(totals + 3) + 511) & ~(size_t)511);
  bf16* fa  = (bf16*)p2;
  bf16* fp_ = fa + (size_t)kNA * 256;
  char* R   = (char*)(fp_ + (size_t)kNP * 256);
  bf16* qa    = (bf16*)R;                   // [NA,256]
  bf16* qp    = qa + (size_t)kNA * 256;     // [NP,256]
  bf16* km_a  = qp + (size_t)kNP * 256;     // [NA,512] writes-KM
  bf16* km_cp = km_a + (size_t)kNA * 512;   // [NP,512] cites-KM
  bf16* km_wbp= km_cp + (size_t)kNP * 512;  // [NP,512] wb-KM
  float* tr_a = (float*)R;                  // fp32 view, disjoint lifetime
  float* tr_p = tr_a + (size_t)kNA * 256;
  char* afterR = (char*)(km_wbp + (size_t)kNP * 512);
  bf16* agg_a = (bf16*)afterR;
  bf16* agg_p = agg_a + (size_t)kNA * 256;

  const bf16* c_ew_wb = canon + kOff(0);
  const bf16* c_ew_w  = canon + kOff(1);
  const bf16* c_ew_c  = canon + kOff(2);
  const bf16* c_adW   = canon + kOff(3);
  const bf16* c_adb   = canon + kOff(4);
  const bf16* c_kW    = canon + kOff(5);
  const bf16* c_kb    = canon + kOff(6);
  const bf16* c_qW    = canon + kOff(7);
  const bf16* c_qb    = canon + kOff(8);
  const bf16* c_mW    = canon + kOff(9);
  const bf16* c_mb    = canon + kOff(10);
  const bf16* c_aW    = canon + kOff(11);
  const bf16* c_ab    = canon + kOff(12);
  const bf16* c_wpri  = canon + kOff(13);
  const bf16* c_watt  = canon + kOff(14);
  const bf16* c_wmsg  = canon + kOff(15);
  const bf16* c_skip  = canon + kOff(16);
  const bf16* c_lng   = canon + kOff(17);
  const bf16* c_lnb   = canon + kOff(18);
  const bf16* c_outW  = canon + kOff(19);
  const bf16* c_outb  = canon + kOff(20);

  const unsigned* fIn = flags + 0;
  const unsigned* f1  = flags + 1;

  detect_dtype<<<1, 256, 0, stream>>>((const unsigned*)d_in[0], flags);

  CanonArgs ca;
  for (int s = 0; s < kNSeg; ++s) { ca.n[s] = kSegN[s]; ca.dstOff[s] = (unsigned)kOff(s); }
  const int srcIdx[kNSeg] = {2,3,4, 5,6, 7,8, 9,10, 11,12, 13,14, 15, 16,17, 18,19,20, 21,22};
  for (int s = 0; s < kNSeg; ++s) ca.src[s] = d_in[srcIdx[s]];
  canon_kernel<<<dim3(1172, kNSeg), 256, 0, stream>>>(ca, canon, flags);

  TransArgs ta;
  ta.src[0] = c_adW;              ta.dst[0] = adWT;
  ta.src[1] = c_adW + 65536;      ta.dst[1] = adWT + 65536;
  for (int m = 0; m < 4; ++m) { ta.src[2 + m] = c_qW + (size_t)m * 65536; ta.dst[2 + m] = qWT + (size_t)m * 65536; }
  for (int m = 0; m < 4; ++m) { ta.src[6 + m] = c_aW + (size_t)m * 65536; ta.dst[6 + m] = aWT + (size_t)m * 65536; }
  transpose_w<<<dim3(4, 4, 10), 256, 0, stream>>>(ta);

  // ---- CSR build ----
  hipMemsetAsync(cur_wb, 0, (size_t)((kNA + 1) + 2 * (kNP + 1)) * 4, stream);
  HistArgs ha;
  ha.dst[0] = dst_wb; ha.cnt[0] = cur_wb; ha.E[0] = kEWB;
  ha.dst[1] = dst_w;  ha.cnt[1] = cur_w;  ha.E[1] = kEW;
  ha.dst[2] = dst_c;  ha.cnt[2] = cur_c;  ha.E[2] = kEC;
  csr_hist<<<dim3((kEC + 255) / 256, 3), 256, 0, stream>>>(ha);
  ScanArgs sa;
  sa.deg[0] = cur_wb;  sa.offs[0] = offs_wb; sa.N[0] = kNA;
  sa.deg[1] = cur_w;   sa.offs[1] = offs_w;  sa.N[1] = kNP;
  sa.deg[2] = cur_c;   sa.offs[2] = offs_c;  sa.N[2] = kNP;
  sa.bsums = bsums;
  scan_l1<<<dim3(32, 3), 256, 0, stream>>>(sa);
  scan_l2<<<3, 64, 0, stream>>>(bsums, totals);
  scan_l3<<<dim3(20, 3), 256, 0, stream>>>(sa, totals);
  ScatArgs sc;
  sc.dst[0] = dst_wb; sc.src[0] = src_wb; sc.ew[0] = c_ew_wb; sc.cur[0] = cur_wb;
  sc.srcs[0] = srcs_wb; sc.ews[0] = ews_wb; sc.E[0] = kEWB;
  sc.dst[1] = dst_w;  sc.src[1] = src_w;  sc.ew[1] = c_ew_w;  sc.cur[1] = cur_w;
  sc.srcs[1] = srcs_w;  sc.ews[1] = ews_w;  sc.E[1] = kEW;
  sc.dst[2] = dst_c;  sc.src[2] = src_c;  sc.ew[2] = c_ew_c;  sc.cur[2] = cur_c;
  sc.srcs[2] = srcs_c;  sc.ews[2] = ews_c;  sc.E[2] = kEC;
  csr_scatter<<<dim3((kEC + 255) / 256, 3), 256, 0, stream>>>(sc);

  combine_weights<<<dim3(8, 24), 256, 0, stream>>>(c_kW, c_kb, c_watt, KMeffT, kmbeT, 0);
  combine_weights<<<dim3(8, 24), 256, 0, stream>>>(c_mW, c_mb, c_wmsg, KMeffT, kmbeT, 256);

  const int ntA = (kNA + 127) / 128;   // 157
  const int ntP = (kNP + 127) / 128;   // 313
  auto sgrid = [](int maxnt, int nslab) {
    return dim3((unsigned)(((maxnt + 7) / 8) * 8 * nslab));
  };
  auto mkd = [](const bf16* wt, const bf16* bias, const void* A, void* c,
                int ldc, int coff, int act, int otype, int M, int ntiles) {
    GemmDesc g;
    g.wt = (const short*)wt; g.bias = bias; g.A = A; g.c = c; g.ldc = ldc;
    g.coff = coff; g.act = act; g.otype = otype; g.M = M; g.ntiles = ntiles;
    return g;
  };

  // adapt: split dispatches (r12 fused version regressed)
  {
    MultiDesc md{};
    md.d[0] = mkd(adWT,             c_adb,       d_in[0], fa, 256, 0,   1, 0, kNA, ntA);
    md.d[1] = mkd(adWT + 128 * 256, c_adb + 128, d_in[0], fa, 256, 128, 1, 0, kNA, ntA);
    mfma_gemm128<<<sgrid(ntA, 2), 256, 0, stream>>>(fIn, md, 2);
    md.d[0] = mkd(adWT + 65536,             c_adb + 256, d_in[1], fp_, 256, 0,   1, 0, kNP, ntP);
    md.d[1] = mkd(adWT + 65536 + 128 * 256, c_adb + 384, d_in[1], fp_, 256, 128, 1, 0, kNP, ntP);
    mfma_gemm128<<<sgrid(ntP, 2), 256, 0, stream>>>(fIn, md, 2);
  }

  for (int l = 0; l < 2; ++l) {
    const bf16* qW_a = qWT + (size_t)(l * 2 + 0) * 65536;
    const bf16* qW_p = qWT + (size_t)(l * 2 + 1) * 65536;
    const bf16* qb_a = c_qb + (l * 2 + 0) * 256;
    const bf16* qb_p = c_qb + (l * 2 + 1) * 256;
    const bf16* KM_c  = KMeffT + (size_t)(l * 3 + 0) * 512 * 256;
    const bf16* KM_w  = KMeffT + (size_t)(l * 3 + 1) * 512 * 256;
    const bf16* KM_wb = KMeffT + (size_t)(l * 3 + 2) * 512 * 256;
    const bf16* kb_c  = kmbeT + (l * 3 + 0) * 512;
    const bf16* kb_w  = kmbeT + (l * 3 + 1) * 512;
    const bf16* kb_wb = kmbeT + (l * 3 + 2) * 512;

    // (1) mega-GEMM: all projections for this layer in ONE dispatch
    {
      MultiDesc md{};
      md.d[0] = mkd(qW_p,             qb_p,       fp_, qp, 256, 0,   0, 0, kNP, ntP);
      md.d[1] = mkd(qW_p + 128 * 256, qb_p + 128, fp_, qp, 256, 128, 0, 0, kNP, ntP);
      for (int s = 0; s < 4; ++s)
        md.d[2 + s] = mkd(KM_c + (size_t)s * 128 * 256, kb_c + s * 128, fp_, km_cp, 512, s * 128, 0, 0, kNP, ntP);
      md.d[6] = mkd(qW_a,             qb_a,       fa, qa, 256, 0,   0, 0, kNA, ntA);
      md.d[7] = mkd(qW_a + 128 * 256, qb_a + 128, fa, qa, 256, 128, 0, 0, kNA, ntA);
      for (int s = 0; s < 4; ++s)
        md.d[8 + s] = mkd(KM_w + (size_t)s * 128 * 256, kb_w + s * 128, fa, km_a, 512, s * 128, 0, 0, kNA, ntA);
      for (int s = 0; s < 4; ++s)
        md.d[12 + s] = mkd(KM_wb + (size_t)s * 128 * 256, kb_wb + s * 128, fp_, km_wbp, 512, s * 128, 0, 0, kNP, ntP);
      mfma_gemm128<<<sgrid(ntP, 16), 256, 0, stream>>>(f1, md, 16);
    }
    // (2) tri-gather: authors (wb) + papers (cites + writes)
    {
      TriDesc td;
      td.qa = qa; td.qp = qp;
      td.km_wb = km_wbp; td.km_c = km_cp; td.km_w = km_a;
      td.srcs_wb = srcs_wb; td.srcs_c = srcs_c; td.srcs_w = srcs_w;
      td.ews_wb = ews_wb; td.ews_c = ews_c; td.ews_w = ews_w;
      td.offs_wb = offs_wb; td.offs_c = offs_c; td.offs_w = offs_w;
      td.pri_wb = c_wpri + (l * 3 + 2) * 4;
      td.pri_c  = c_wpri + (l * 3 + 0) * 4;
      td.pri_w  = c_wpri + (l * 3 + 1) * 4;
      td.agg_a = agg_a; td.agg_p = agg_p;
      const int bA = (kNA + 3) / 4;
      tri_gather<<<bA + (kNP + 3) / 4, 256, 0, stream>>>(td, bA);
    }
    // (3) fused A-projection (authors + papers) -> fp32 tr
    {
      const bf16* aW_a = aWT + (size_t)(l * 2 + 0) * 65536;
      const bf16* aW_p = aWT + (size_t)(l * 2 + 1) * 65536;
      MultiDesc md{};
      md.d[0] = mkd(aW_a,             c_ab + (l * 2 + 0) * 256,       agg_a, tr_a, 256, 0,   0, 1, kNA, ntA);
      md.d[1] = mkd(aW_a + 128 * 256, c_ab + (l * 2 + 0) * 256 + 128, agg_a, tr_a, 256, 128, 0, 1, kNA, ntA);
      md.d[2] = mkd(aW_p,             c_ab + (l * 2 + 1) * 256,       agg_p, tr_p, 256, 0,   0, 1, kNP, ntP);
      md.d[3] = mkd(aW_p + 128 * 256, c_ab + (l * 2 + 1) * 256 + 128, agg_p, tr_p, 256, 128, 0, 1, kNP, ntP);
      mfma_gemm128<<<sgrid(ntP, 4), 256, 0, stream>>>(f1, md, 4);
    }
    // (4) fused skip+LN
    skip_ln2<<<(kNA + kNP) / 4, 256, 0, stream>>>(
        tr_a, fa,  c_skip + l * 3 + 0, c_lng + (l * 2 + 0) * 256, c_lnb + (l * 2 + 0) * 256,
        tr_p, fp_, c_skip + l * 3 + 1, c_lng + (l * 2 + 1) * 256, c_lnb + (l * 2 + 1) * 256,
        kNA, kNA + kNP);
  }

  out_gemm<<<kNP / 64, 256, 0, stream>>>(fp_, c_outW, c_outb, d_out, fIn, kNP);
}